// Round 1
// baseline (606.570 us; speedup 1.0000x reference)
//
#include <hip/hip_runtime.h>
#include <hip/hip_bf16.h>
#include <stdint.h>

// Problem constants: B=2, S=2048, D=2048, H=32, HD=64, 3D=6144, M=B*S=4096, K=2048
typedef unsigned short ushort_t;
typedef __bf16 bf16x8 __attribute__((ext_vector_type(8)));
typedef float f32x4 __attribute__((ext_vector_type(4)));
typedef ushort_t ushort8 __attribute__((ext_vector_type(8)));

__device__ __forceinline__ ushort_t f2bf(float f) {
  union { float f; unsigned int u; } v; v.f = f;
  unsigned int r = v.u + 0x7fffu + ((v.u >> 16) & 1u);  // RNE
  return (ushort_t)(r >> 16);
}

__device__ __forceinline__ bf16x8 ld_bf8(const ushort_t* p) {
  return *reinterpret_cast<const bf16x8*>(p);
}

__device__ __forceinline__ void g2lds16(const void* g, void* l) {
  __builtin_amdgcn_global_load_lds(
      (const __attribute__((address_space(1))) unsigned int*)g,
      (__attribute__((address_space(3))) unsigned int*)l,
      16, 0, 0);
}

// ---------------- Pass 0a: hidden_states f32 -> bf16 (same layout) ----------
__global__ __launch_bounds__(256) void cvt_hs(const float* __restrict__ in,
                                              ushort_t* __restrict__ out) {
  int i = (blockIdx.x * 256 + threadIdx.x) * 8;
  float4 a = *reinterpret_cast<const float4*>(in + i);
  float4 b = *reinterpret_cast<const float4*>(in + i + 4);
  ushort8 r;
  r[0] = f2bf(a.x); r[1] = f2bf(a.y); r[2] = f2bf(a.z); r[3] = f2bf(a.w);
  r[4] = f2bf(b.x); r[5] = f2bf(b.y); r[6] = f2bf(b.z); r[7] = f2bf(b.w);
  *reinterpret_cast<ushort8*>(out + i) = r;
}

// ---------------- Pass 0b: W [2048][6144] f32 -> Wt [6144][2048] bf16 -------
__global__ __launch_bounds__(256) void transpose_W(const float* __restrict__ Win,
                                                   ushort_t* __restrict__ Wt) {
  __shared__ ushort_t T[64][65];  // +1 pad -> conflict-free both sides
  const int t = threadIdx.x;
  const int k0 = (blockIdx.x & 31) * 64;   // 2048/64 = 32 k-tiles
  const int n0 = (blockIdx.x >> 5) * 64;   // 6144/64 = 96 n-tiles
#pragma unroll
  for (int i = 0; i < 16; ++i) {
    int idx = i * 256 + t;
    int r = idx >> 6, c = idx & 63;
    T[r][c] = f2bf(Win[(k0 + r) * 6144 + n0 + c]);
  }
  __syncthreads();
#pragma unroll
  for (int i = 0; i < 16; ++i) {
    int idx = i * 256 + t;
    int nr = idx >> 6, kc = idx & 63;
    Wt[(n0 + nr) * 2048 + k0 + kc] = T[kc][nr];
  }
}

// ---------------- Pass 1: QKV GEMM (m97 structure, bf16 MFMA) ---------------
// C[m][n] = A[m][:] . Bt[n][:], + bias[n]; epilogue de-interleaves n%3:
//   ch0 -> Qb[bh][s][hd] (scaled 1/8), ch1 -> VT[bh][hd][s], ch2 -> Kb[bh][s][hd]
__global__ __launch_bounds__(256, 2) void gemm_qkv(
    const ushort_t* __restrict__ A, const ushort_t* __restrict__ Bt,
    const float* __restrict__ bias,
    ushort_t* __restrict__ Qb, ushort_t* __restrict__ Kb,
    ushort_t* __restrict__ VT) {
  __shared__ __align__(16) ushort_t As[128 * 32];
  __shared__ __align__(16) ushort_t Bs[128 * 32];
  const int t = threadIdx.x;
  const int w = t >> 6, l = t & 63;
  const int lo = l & 15, hi = l >> 4;
  const int wr = w >> 1, wc = w & 1;

  // XCD-aware swizzle: 1536 blocks = 8 * 192 (bijective)
  int bid = blockIdx.x;
  int swz = (bid & 7) * 192 + (bid >> 3);
  const int bm = (swz & 31) * 128;   // 32 m-tiles
  const int bn = (swz >> 5) * 128;   // 48 n-tiles

  f32x4 acc[4][4];
#pragma unroll
  for (int i = 0; i < 4; ++i)
#pragma unroll
    for (int j = 0; j < 4; ++j) acc[i][j] = f32x4{0.f, 0.f, 0.f, 0.f};

  const ushort_t* Ag = A + bm * 2048;
  const ushort_t* Bg = Bt + bn * 2048;

  for (int kk = 0; kk < 2048; kk += 32) {
    // stage 8KB A + 8KB B; linear LDS dest, inverse-swizzled global source
#pragma unroll
    for (int r2 = 0; r2 < 2; ++r2) {
      int c = r2 * 256 + t;
      int row = c >> 2, s4 = c & 3;
      int slot = s4 ^ (row & 3);
      g2lds16(Ag + row * 2048 + kk + slot * 8, As + c * 8);
      g2lds16(Bg + row * 2048 + kk + slot * 8, Bs + c * 8);
    }
    __syncthreads();
    bf16x8 af[4], bfr[4];
#pragma unroll
    for (int mf = 0; mf < 4; ++mf) {
      int row = wr * 64 + mf * 16 + lo;
      af[mf] = ld_bf8(As + row * 32 + ((hi ^ (row & 3)) << 3));
    }
#pragma unroll
    for (int nf = 0; nf < 4; ++nf) {
      int row = wc * 64 + nf * 16 + lo;
      bfr[nf] = ld_bf8(Bs + row * 32 + ((hi ^ (row & 3)) << 3));
    }
#pragma unroll
    for (int mf = 0; mf < 4; ++mf)
#pragma unroll
      for (int nf = 0; nf < 4; ++nf)
        acc[mf][nf] = __builtin_amdgcn_mfma_f32_16x16x32_bf16(
            af[mf], bfr[nf], acc[mf][nf], 0, 0, 0);
    __syncthreads();
  }

  // epilogue: bias + de-interleave scatter (bf16 scalar stores)
#pragma unroll
  for (int nf = 0; nf < 4; ++nf) {
    int n = bn + wc * 64 + nf * 16 + lo;
    float bv = bias[n];
    int d = (int)((unsigned)n / 3u);
    int ch = n - d * 3;
    int h = d >> 6, hd = d & 63;
#pragma unroll
    for (int mf = 0; mf < 4; ++mf) {
      f32x4 a = acc[mf][nf];
#pragma unroll
      for (int j = 0; j < 4; ++j) {
        int m = bm + wr * 64 + mf * 16 + hi * 4 + j;
        int b_ = m >> 11, s = m & 2047;
        int bh = (b_ << 5) + h;
        float v = a[j] + bv;
        if (ch == 0)
          Qb[(bh * 2048 + s) * 64 + hd] = f2bf(v * 0.125f);  // fold 1/sqrt(64)
        else if (ch == 1)
          VT[(bh * 64 + hd) * 2048 + s] = f2bf(v);
        else
          Kb[(bh * 2048 + s) * 64 + hd] = f2bf(v);
      }
    }
  }
}

// ---------------- Pass 2: causal flash attention ----------------------------
// grid = 64 bh * 32 qtiles; 4 waves/block, each wave owns 16 q-rows.
__global__ __launch_bounds__(256, 2) void attn(
    const ushort_t* __restrict__ Qb, const ushort_t* __restrict__ Kb,
    const ushort_t* __restrict__ VT, float* __restrict__ out) {
  __shared__ __align__(16) ushort_t Pl[4][16 * 32];  // per-wave P buffer
  const int t = threadIdx.x;
  const int w = t >> 6, l = t & 63;
  const int lo = l & 15, hi = l >> 4;
  const int bh = blockIdx.x >> 5;
  const int qt = blockIdx.x & 31;
  const int q0 = qt * 64 + w * 16;

  const ushort_t* qp = Qb + (bh * 2048 + q0 + lo) * 64 + hi * 8;
  bf16x8 qf0 = ld_bf8(qp);        // hd 0..31 slice
  bf16x8 qf1 = ld_bf8(qp + 32);   // hd 32..63 slice

  f32x4 O[4];
  float mr[4], lr[4];
#pragma unroll
  for (int j = 0; j < 4; ++j) {
    O[j] = f32x4{0.f, 0.f, 0.f, 0.f};
    mr[j] = -1e30f;
    lr[j] = 0.f;
  }

  ushort_t* pl = &Pl[w][0];
  const int nch = (q0 + 16 + 31) >> 5;  // 32-wide k chunks, causal bound
  for (int c = 0; c < nch; ++c) {
    const int kb = c << 5;
    const ushort_t* kp = Kb + (bh * 2048 + kb + lo) * 64 + hi * 8;
    bf16x8 k00 = ld_bf8(kp), k01 = ld_bf8(kp + 32);
    bf16x8 k10 = ld_bf8(kp + 16 * 64), k11 = ld_bf8(kp + 16 * 64 + 32);
    f32x4 s0 = f32x4{0.f, 0.f, 0.f, 0.f};
    f32x4 s1 = f32x4{0.f, 0.f, 0.f, 0.f};
    s0 = __builtin_amdgcn_mfma_f32_16x16x32_bf16(qf0, k00, s0, 0, 0, 0);
    s0 = __builtin_amdgcn_mfma_f32_16x16x32_bf16(qf1, k01, s0, 0, 0, 0);
    s1 = __builtin_amdgcn_mfma_f32_16x16x32_bf16(qf0, k10, s1, 0, 0, 0);
    s1 = __builtin_amdgcn_mfma_f32_16x16x32_bf16(qf1, k11, s1, 0, 0, 0);

    if (kb + 31 > q0) {  // diagonal region: per-element causal mask
#pragma unroll
      for (int j = 0; j < 4; ++j) {
        int q = q0 + hi * 4 + j;
        if (kb + lo > q) s0[j] = -1e30f;
        if (kb + 16 + lo > q) s1[j] = -1e30f;
      }
    }
    // online softmax; row r = hi*4+j, cols split across 16 lanes (lo)
    float mx[4], pr[4], scl[4];
#pragma unroll
    for (int j = 0; j < 4; ++j) mx[j] = fmaxf(s0[j], s1[j]);
#pragma unroll
    for (int off = 1; off < 16; off <<= 1)
#pragma unroll
      for (int j = 0; j < 4; ++j) mx[j] = fmaxf(mx[j], __shfl_xor(mx[j], off));
#pragma unroll
    for (int j = 0; j < 4; ++j) {
      float mn = fmaxf(mr[j], mx[j]);
      scl[j] = __expf(mr[j] - mn);
      mr[j] = mn;
      s0[j] = __expf(s0[j] - mn);
      s1[j] = __expf(s1[j] - mn);
      pr[j] = s0[j] + s1[j];
    }
#pragma unroll
    for (int off = 1; off < 16; off <<= 1)
#pragma unroll
      for (int j = 0; j < 4; ++j) pr[j] += __shfl_xor(pr[j], off);
#pragma unroll
    for (int j = 0; j < 4; ++j) lr[j] = lr[j] * scl[j] + pr[j];
#pragma unroll
    for (int nf = 0; nf < 4; ++nf)
#pragma unroll
      for (int j = 0; j < 4; ++j) O[nf][j] *= scl[j];

    // P -> wave-private LDS (granule-XOR swizzled), then re-fragment as A
#pragma unroll
    for (int j = 0; j < 4; ++j) {
      int row = hi * 4 + j;
      int pc0 = (((lo >> 3) ^ (row & 3)) << 3) | (lo & 7);
      int pc1 = ((((16 + lo) >> 3) ^ (row & 3)) << 3) | (lo & 7);
      pl[row * 32 + pc0] = f2bf(s0[j]);
      pl[row * 32 + pc1] = f2bf(s1[j]);
    }
    bf16x8 pf = ld_bf8(pl + lo * 32 + ((hi ^ (lo & 3)) << 3));
    // PV: B-frag from VT[bh][hd][s] — contiguous in k
#pragma unroll
    for (int nf = 0; nf < 4; ++nf) {
      const ushort_t* vp = VT + (bh * 64 + nf * 16 + lo) * 2048 + kb + hi * 8;
      bf16x8 vf = ld_bf8(vp);
      O[nf] = __builtin_amdgcn_mfma_f32_16x16x32_bf16(pf, vf, O[nf], 0, 0, 0);
    }
  }

  const int b_ = bh >> 5, h = bh & 31;
  float inv[4];
#pragma unroll
  for (int j = 0; j < 4; ++j) inv[j] = 1.f / lr[j];
#pragma unroll
  for (int nf = 0; nf < 4; ++nf)
#pragma unroll
    for (int j = 0; j < 4; ++j) {
      int q = q0 + hi * 4 + j;
      out[(b_ * 2048 + q) * 2048 + h * 64 + nf * 16 + lo] = O[nf][j] * inv[j];
    }
}

// ---------------------------------------------------------------------------
extern "C" void kernel_launch(void* const* d_in, const int* in_sizes, int n_in,
                              void* d_out, int out_size, void* d_ws,
                              size_t ws_size, hipStream_t stream) {
  (void)in_sizes; (void)n_in; (void)out_size; (void)ws_size;
  const float* hs = (const float*)d_in[0];    // [2,2048,2048]
  const float* W = (const float*)d_in[1];     // [2048,6144]
  const float* bias = (const float*)d_in[2];  // [6144]
  float* out = (float*)d_out;

  char* ws = (char*)d_ws;
  ushort_t* Abf = (ushort_t*)(ws);                        // 16 MiB  [4096][2048]
  ushort_t* Wt = (ushort_t*)(ws + (16u << 20));           // 24 MiB  [6144][2048]
  ushort_t* Qb = (ushort_t*)(ws + (40u << 20));           // 16 MiB  [64][2048][64]
  ushort_t* Kb = (ushort_t*)(ws + (56u << 20));           // 16 MiB  [64][2048][64]
  ushort_t* VT = (ushort_t*)(ws + (72u << 20));           // 16 MiB  [64][64][2048]

  hipLaunchKernelGGL(cvt_hs, dim3(4096), dim3(256), 0, stream, hs, Abf);
  hipLaunchKernelGGL(transpose_W, dim3(3072), dim3(256), 0, stream, W, Wt);
  hipLaunchKernelGGL(gemm_qkv, dim3(1536), dim3(256), 0, stream, Abf, Wt, bias,
                     Qb, Kb, VT);
  hipLaunchKernelGGL(attn, dim3(2048), dim3(256), 0, stream, Qb, Kb, VT, out);
}

// Round 2
// 388.776 us; speedup vs baseline: 1.5602x; 1.5602x over previous
//
#include <hip/hip_runtime.h>
#include <hip/hip_bf16.h>
#include <stdint.h>

// Problem constants: B=2, S=2048, D=2048, H=32, HD=64, 3D=6144, M=B*S=4096, K=2048
typedef unsigned short ushort_t;
typedef __bf16 bf16x8 __attribute__((ext_vector_type(8)));
typedef float f32x4 __attribute__((ext_vector_type(4)));
typedef float f32x16 __attribute__((ext_vector_type(16)));
typedef int int4v __attribute__((ext_vector_type(4)));
typedef ushort_t ushort8 __attribute__((ext_vector_type(8)));

__device__ __forceinline__ ushort_t f2bf(float f) {
  union { float f; unsigned int u; } v; v.f = f;
  unsigned int r = v.u + 0x7fffu + ((v.u >> 16) & 1u);  // RNE
  return (ushort_t)(r >> 16);
}

__device__ __forceinline__ bf16x8 ld_bf8(const ushort_t* p) {
  return *reinterpret_cast<const bf16x8*>(p);
}

__device__ __forceinline__ void g2lds16(const void* g, void* l) {
  __builtin_amdgcn_global_load_lds(
      (const __attribute__((address_space(1))) unsigned int*)g,
      (__attribute__((address_space(3))) unsigned int*)l,
      16, 0, 0);
}

__device__ __forceinline__ float ex2(float x) { return __builtin_amdgcn_exp2f(x); }

// v_cvt_pk_bf16_f32: word = {lo: bf16(a), hi: bf16(b)}
__device__ __forceinline__ int cvtpk(float a, float b) {
  int r;
  asm("v_cvt_pk_bf16_f32 %0, %1, %2" : "=v"(r) : "v"(a), "v"(b));
  return r;
}

// ---------------- Pass 0a: hidden_states f32 -> bf16 (same layout) ----------
__global__ __launch_bounds__(256) void cvt_hs(const float* __restrict__ in,
                                              ushort_t* __restrict__ out) {
  int i = (blockIdx.x * 256 + threadIdx.x) * 8;
  float4 a = *reinterpret_cast<const float4*>(in + i);
  float4 b = *reinterpret_cast<const float4*>(in + i + 4);
  ushort8 r;
  r[0] = f2bf(a.x); r[1] = f2bf(a.y); r[2] = f2bf(a.z); r[3] = f2bf(a.w);
  r[4] = f2bf(b.x); r[5] = f2bf(b.y); r[6] = f2bf(b.z); r[7] = f2bf(b.w);
  *reinterpret_cast<ushort8*>(out + i) = r;
}

// ---------------- Pass 0b: W [2048][6144] f32 -> Wt [6144][2048] bf16 -------
__global__ __launch_bounds__(256) void transpose_W(const float* __restrict__ Win,
                                                   ushort_t* __restrict__ Wt) {
  __shared__ ushort_t T[64][65];
  const int t = threadIdx.x;
  const int k0 = (blockIdx.x & 31) * 64;
  const int n0 = (blockIdx.x >> 5) * 64;
#pragma unroll
  for (int i = 0; i < 16; ++i) {
    int idx = i * 256 + t;
    int r = idx >> 6, c = idx & 63;
    T[r][c] = f2bf(Win[(k0 + r) * 6144 + n0 + c]);
  }
  __syncthreads();
#pragma unroll
  for (int i = 0; i < 16; ++i) {
    int idx = i * 256 + t;
    int nr = idx >> 6, kc = idx & 63;
    Wt[(n0 + nr) * 2048 + k0 + kc] = T[kc][nr];
  }
}

// ---------------- Pass 1: QKV GEMM (m97 structure, bf16 MFMA) ---------------
// Q pre-scaled by 0.125*log2(e) so attention can use exp2 directly.
__global__ __launch_bounds__(256, 2) void gemm_qkv(
    const ushort_t* __restrict__ A, const ushort_t* __restrict__ Bt,
    const float* __restrict__ bias,
    ushort_t* __restrict__ Qb, ushort_t* __restrict__ Kb,
    ushort_t* __restrict__ VT) {
  __shared__ __align__(16) ushort_t As[128 * 32];
  __shared__ __align__(16) ushort_t Bs[128 * 32];
  const int t = threadIdx.x;
  const int w = t >> 6, l = t & 63;
  const int lo = l & 15, hi = l >> 4;
  const int wr = w >> 1, wc = w & 1;

  int bid = blockIdx.x;
  int swz = (bid & 7) * 192 + (bid >> 3);
  const int bm = (swz & 31) * 128;
  const int bn = (swz >> 5) * 128;

  f32x4 acc[4][4];
#pragma unroll
  for (int i = 0; i < 4; ++i)
#pragma unroll
    for (int j = 0; j < 4; ++j) acc[i][j] = f32x4{0.f, 0.f, 0.f, 0.f};

  const ushort_t* Ag = A + bm * 2048;
  const ushort_t* Bg = Bt + bn * 2048;

  for (int kk = 0; kk < 2048; kk += 32) {
#pragma unroll
    for (int r2 = 0; r2 < 2; ++r2) {
      int c = r2 * 256 + t;
      int row = c >> 2, s4 = c & 3;
      int slot = s4 ^ (row & 3);
      g2lds16(Ag + row * 2048 + kk + slot * 8, As + c * 8);
      g2lds16(Bg + row * 2048 + kk + slot * 8, Bs + c * 8);
    }
    __syncthreads();
    bf16x8 af[4], bfr[4];
#pragma unroll
    for (int mf = 0; mf < 4; ++mf) {
      int row = wr * 64 + mf * 16 + lo;
      af[mf] = ld_bf8(As + row * 32 + ((hi ^ (row & 3)) << 3));
    }
#pragma unroll
    for (int nf = 0; nf < 4; ++nf) {
      int row = wc * 64 + nf * 16 + lo;
      bfr[nf] = ld_bf8(Bs + row * 32 + ((hi ^ (row & 3)) << 3));
    }
#pragma unroll
    for (int mf = 0; mf < 4; ++mf)
#pragma unroll
      for (int nf = 0; nf < 4; ++nf)
        acc[mf][nf] = __builtin_amdgcn_mfma_f32_16x16x32_bf16(
            af[mf], bfr[nf], acc[mf][nf], 0, 0, 0);
    __syncthreads();
  }

#pragma unroll
  for (int nf = 0; nf < 4; ++nf) {
    int n = bn + wc * 64 + nf * 16 + lo;
    float bv = bias[n];
    int d = (int)((unsigned)n / 3u);
    int ch = n - d * 3;
    int h = d >> 6, hd = d & 63;
#pragma unroll
    for (int mf = 0; mf < 4; ++mf) {
      f32x4 a = acc[mf][nf];
#pragma unroll
      for (int j = 0; j < 4; ++j) {
        int m = bm + wr * 64 + mf * 16 + hi * 4 + j;
        int b_ = m >> 11, s = m & 2047;
        int bh = (b_ << 5) + h;
        float v = a[j] + bv;
        if (ch == 0)
          Qb[(bh * 2048 + s) * 64 + hd] = f2bf(v * (0.125f * 1.44269504f));
        else if (ch == 1)
          VT[(bh * 64 + hd) * 2048 + s] = f2bf(v);
        else
          Kb[(bh * 2048 + s) * 64 + hd] = f2bf(v);
      }
    }
  }
}

// ---------------- Pass 2: causal flash attention (swapped QK^T, 32x32x16) ---
// grid = 64 bh * 16 qtiles; 4 waves/block, each wave owns 32 q-rows.
// Swapped layout: P^T = mfma(A=K_tile, B=Q^T): lane holds col q=l&31, 16 kv regs.
// PV swapped: O^T = mfma(A=V^T, B=P^T). Softmax fully in-register.
__global__ __launch_bounds__(256, 3) void attn(
    const ushort_t* __restrict__ Qb, const ushort_t* __restrict__ Kb,
    const ushort_t* __restrict__ VT, float* __restrict__ out) {
  __shared__ float Ol[4][32 * 65];  // per-wave 32q x 64hd, stride 65 (bank-safe)
  const int t = threadIdx.x;
  const int w = t >> 6, l = t & 63;
  const int ql = l & 31, hi = l >> 5;

  int bid = blockIdx.x;
  int swz = (bid & 7) * 128 + (bid >> 3);  // bijective XCD swizzle (1024=8*128)
  const int bh = swz >> 4;
  const int qt = swz & 15;
  const int q0 = qt * 128 + w * 32;

  // Q fragments (B operand): lane: col q = ql, k = d = dc*16 + hi*8 + j
  const ushort_t* qp = Qb + (bh * 2048 + q0 + ql) * 64 + hi * 8;
  bf16x8 qf[4];
#pragma unroll
  for (int dc = 0; dc < 4; ++dc) qf[dc] = ld_bf8(qp + dc * 16);

  f32x16 o0, o1;
#pragma unroll
  for (int r = 0; r < 16; ++r) { o0[r] = 0.f; o1[r] = 0.f; }
  float mr = -1e30f, lr = 0.f;

  const int nch = (q0 >> 5) + 1;  // causal: chunks 0..q0/32 inclusive
  for (int c = 0; c < nch; ++c) {
    const int kb = c << 5;
    // K fragments (A operand): lane: row kv = ql, k = d
    const ushort_t* kp = Kb + (bh * 2048 + kb + ql) * 64 + hi * 8;
    f32x16 p;
#pragma unroll
    for (int r = 0; r < 16; ++r) p[r] = 0.f;
#pragma unroll
    for (int dc = 0; dc < 4; ++dc)
      p = __builtin_amdgcn_mfma_f32_32x32x16_bf16(ld_bf8(kp + dc * 16), qf[dc],
                                                  p, 0, 0, 0);
    // p[r] = S^T[kv = (r&3)+8*(r>>2)+4*hi][q = ql]  (log2-domain scores)
    if (c == nch - 1) {  // diagonal chunk: mask kv > q
#pragma unroll
      for (int r = 0; r < 16; ++r) {
        int kvr = (r & 3) + 8 * (r >> 2) + 4 * hi;
        if (kvr > ql) p[r] = -1e30f;
      }
    }
    // row max: 15 in-lane + 1 cross (lane^32 holds other 16 kv of same q)
    float mx = p[0];
#pragma unroll
    for (int r = 1; r < 16; ++r) mx = fmaxf(mx, p[r]);
    mx = fmaxf(mx, __shfl_xor(mx, 32));
    float mn = fmaxf(mr, mx);
    float scl = ex2(mr - mn);
    mr = mn;
    float sum = 0.f;
#pragma unroll
    for (int r = 0; r < 16; ++r) {
      p[r] = ex2(p[r] - mn);
      sum += p[r];
    }
    sum += __shfl_xor(sum, 32);
    lr = lr * scl + sum;
#pragma unroll
    for (int r = 0; r < 16; ++r) { o0[r] *= scl; o1[r] *= scl; }

    // P^T -> bf16 B-fragments, in-register (cvt_pk + lane^32 exchange)
#pragma unroll
    for (int s = 0; s < 2; ++s) {
      int x0 = cvtpk(p[8 * s + 0], p[8 * s + 1]);
      int x1 = cvtpk(p[8 * s + 2], p[8 * s + 3]);
      int y0 = cvtpk(p[8 * s + 4], p[8 * s + 5]);
      int y1 = cvtpk(p[8 * s + 6], p[8 * s + 7]);
      int ox0 = __shfl_xor(x0, 32);
      int ox1 = __shfl_xor(x1, 32);
      int oy0 = __shfl_xor(y0, 32);
      int oy1 = __shfl_xor(y1, 32);
      int4v wv;
      wv[0] = hi ? oy0 : x0;  // elems j=0,1: kv 16s+8hi+{0,1}
      wv[1] = hi ? oy1 : x1;  // j=2,3
      wv[2] = hi ? y0 : ox0;  // j=4,5
      wv[3] = hi ? y1 : ox1;  // j=6,7
      bf16x8 pf = __builtin_bit_cast(bf16x8, wv);
      // V^T fragments (A operand): row hd = ql (+32 for tile1), k = kv
      const ushort_t* vp = VT + (bh * 64 + ql) * 2048 + kb + s * 16 + hi * 8;
      o0 = __builtin_amdgcn_mfma_f32_32x32x16_bf16(ld_bf8(vp), pf, o0, 0, 0, 0);
      o1 = __builtin_amdgcn_mfma_f32_32x32x16_bf16(ld_bf8(vp + 32 * 2048), pf,
                                                   o1, 0, 0, 0);
    }
  }

  // epilogue: normalize, de-transpose via wave-private LDS, coalesced store
  const float inv = 1.0f / lr;  // lr is per-q (lane), identical across hi pair
  float* Lw = &Ol[w][0];
#pragma unroll
  for (int r = 0; r < 16; ++r) {
    int hdv = (r & 3) + 8 * (r >> 2) + 4 * hi;
    Lw[ql * 65 + hdv] = o0[r] * inv;
    Lw[ql * 65 + 32 + hdv] = o1[r] * inv;
  }
  const int b_ = bh >> 5, h = bh & 31;
  float* op = out + ((size_t)(b_ * 2048 + q0) * 2048) + h * 64 + l;
#pragma unroll
  for (int i = 0; i < 32; ++i) {
    op[i * 2048] = Lw[i * 65 + l];
  }
}

// ---------------------------------------------------------------------------
extern "C" void kernel_launch(void* const* d_in, const int* in_sizes, int n_in,
                              void* d_out, int out_size, void* d_ws,
                              size_t ws_size, hipStream_t stream) {
  (void)in_sizes; (void)n_in; (void)out_size; (void)ws_size;
  const float* hs = (const float*)d_in[0];    // [2,2048,2048]
  const float* W = (const float*)d_in[1];     // [2048,6144]
  const float* bias = (const float*)d_in[2];  // [6144]
  float* out = (float*)d_out;

  char* ws = (char*)d_ws;
  ushort_t* Abf = (ushort_t*)(ws);                        // 16 MiB  [4096][2048]
  ushort_t* Wt = (ushort_t*)(ws + (16u << 20));           // 24 MiB  [6144][2048]
  ushort_t* Qb = (ushort_t*)(ws + (40u << 20));           // 16 MiB  [64][2048][64]
  ushort_t* Kb = (ushort_t*)(ws + (56u << 20));           // 16 MiB  [64][2048][64]
  ushort_t* VT = (ushort_t*)(ws + (72u << 20));           // 16 MiB  [64][64][2048]

  hipLaunchKernelGGL(cvt_hs, dim3(4096), dim3(256), 0, stream, hs, Abf);
  hipLaunchKernelGGL(transpose_W, dim3(3072), dim3(256), 0, stream, W, Wt);
  hipLaunchKernelGGL(gemm_qkv, dim3(1536), dim3(256), 0, stream, Abf, Wt, bias,
                     Qb, Kb, VT);
  hipLaunchKernelGGL(attn, dim3(1024), dim3(256), 0, stream, Qb, Kb, VT, out);
}

// Round 3
// 317.635 us; speedup vs baseline: 1.9096x; 1.2240x over previous
//
#include <hip/hip_runtime.h>
#include <hip/hip_bf16.h>
#include <stdint.h>

// Problem constants: B=2, S=2048, D=2048, H=32, HD=64, 3D=6144, M=B*S=4096, K=2048
typedef unsigned short ushort_t;
typedef __bf16 bf16x8 __attribute__((ext_vector_type(8)));
typedef float f32x4 __attribute__((ext_vector_type(4)));
typedef float f32x16 __attribute__((ext_vector_type(16)));
typedef int int4v __attribute__((ext_vector_type(4)));
typedef ushort_t ushort8 __attribute__((ext_vector_type(8)));

__device__ __forceinline__ ushort_t f2bf(float f) {
  union { float f; unsigned int u; } v; v.f = f;
  unsigned int r = v.u + 0x7fffu + ((v.u >> 16) & 1u);  // RNE
  return (ushort_t)(r >> 16);
}

__device__ __forceinline__ bf16x8 ld_bf8(const ushort_t* p) {
  return *reinterpret_cast<const bf16x8*>(p);
}

__device__ __forceinline__ void g2lds16(const void* g, void* l) {
  __builtin_amdgcn_global_load_lds(
      (const __attribute__((address_space(1))) unsigned int*)g,
      (__attribute__((address_space(3))) unsigned int*)l,
      16, 0, 0);
}

__device__ __forceinline__ float ex2(float x) { return __builtin_amdgcn_exp2f(x); }

// v_cvt_pk_bf16_f32: word = {lo: bf16(a), hi: bf16(b)}
__device__ __forceinline__ int cvtpk(float a, float b) {
  int r;
  asm("v_cvt_pk_bf16_f32 %0, %1, %2" : "=v"(r) : "v"(a), "v"(b));
  return r;
}

// ---------------- Pass 0a: hidden_states f32 -> bf16 (same layout) ----------
__global__ __launch_bounds__(256) void cvt_hs(const float* __restrict__ in,
                                              ushort_t* __restrict__ out) {
  int i = (blockIdx.x * 256 + threadIdx.x) * 8;
  float4 a = *reinterpret_cast<const float4*>(in + i);
  float4 b = *reinterpret_cast<const float4*>(in + i + 4);
  ushort8 r;
  r[0] = f2bf(a.x); r[1] = f2bf(a.y); r[2] = f2bf(a.z); r[3] = f2bf(a.w);
  r[4] = f2bf(b.x); r[5] = f2bf(b.y); r[6] = f2bf(b.z); r[7] = f2bf(b.w);
  *reinterpret_cast<ushort8*>(out + i) = r;
}

// ---------------- Pass 0b: W [2048][6144] f32 -> Wt [6144][2048] bf16 -------
__global__ __launch_bounds__(256) void transpose_W(const float* __restrict__ Win,
                                                   ushort_t* __restrict__ Wt) {
  __shared__ ushort_t T[64][65];
  const int t = threadIdx.x;
  const int k0 = (blockIdx.x & 31) * 64;
  const int n0 = (blockIdx.x >> 5) * 64;
#pragma unroll
  for (int i = 0; i < 16; ++i) {
    int idx = i * 256 + t;
    int r = idx >> 6, c = idx & 63;
    T[r][c] = f2bf(Win[(k0 + r) * 6144 + n0 + c]);
  }
  __syncthreads();
#pragma unroll
  for (int i = 0; i < 16; ++i) {
    int idx = i * 256 + t;
    int nr = idx >> 6, kc = idx & 63;
    Wt[(n0 + nr) * 2048 + k0 + kc] = T[kc][nr];
  }
}

// ---------------- Pass 1: QKV GEMM (m97 structure, bf16 MFMA) ---------------
// Q pre-scaled by 0.125*log2(e) so attention can use exp2 directly.
__global__ __launch_bounds__(256, 2) void gemm_qkv(
    const ushort_t* __restrict__ A, const ushort_t* __restrict__ Bt,
    const float* __restrict__ bias,
    ushort_t* __restrict__ Qb, ushort_t* __restrict__ Kb,
    ushort_t* __restrict__ VT) {
  __shared__ __align__(16) ushort_t As[128 * 32];
  __shared__ __align__(16) ushort_t Bs[128 * 32];
  const int t = threadIdx.x;
  const int w = t >> 6, l = t & 63;
  const int lo = l & 15, hi = l >> 4;
  const int wr = w >> 1, wc = w & 1;

  int bid = blockIdx.x;
  int swz = (bid & 7) * 192 + (bid >> 3);
  const int bm = (swz & 31) * 128;
  const int bn = (swz >> 5) * 128;

  f32x4 acc[4][4];
#pragma unroll
  for (int i = 0; i < 4; ++i)
#pragma unroll
    for (int j = 0; j < 4; ++j) acc[i][j] = f32x4{0.f, 0.f, 0.f, 0.f};

  const ushort_t* Ag = A + bm * 2048;
  const ushort_t* Bg = Bt + bn * 2048;

  for (int kk = 0; kk < 2048; kk += 32) {
#pragma unroll
    for (int r2 = 0; r2 < 2; ++r2) {
      int c = r2 * 256 + t;
      int row = c >> 2, s4 = c & 3;
      int slot = s4 ^ (row & 3);
      g2lds16(Ag + row * 2048 + kk + slot * 8, As + c * 8);
      g2lds16(Bg + row * 2048 + kk + slot * 8, Bs + c * 8);
    }
    __syncthreads();
    bf16x8 af[4], bfr[4];
#pragma unroll
    for (int mf = 0; mf < 4; ++mf) {
      int row = wr * 64 + mf * 16 + lo;
      af[mf] = ld_bf8(As + row * 32 + ((hi ^ (row & 3)) << 3));
    }
#pragma unroll
    for (int nf = 0; nf < 4; ++nf) {
      int row = wc * 64 + nf * 16 + lo;
      bfr[nf] = ld_bf8(Bs + row * 32 + ((hi ^ (row & 3)) << 3));
    }
#pragma unroll
    for (int mf = 0; mf < 4; ++mf)
#pragma unroll
      for (int nf = 0; nf < 4; ++nf)
        acc[mf][nf] = __builtin_amdgcn_mfma_f32_16x16x32_bf16(
            af[mf], bfr[nf], acc[mf][nf], 0, 0, 0);
    __syncthreads();
  }

#pragma unroll
  for (int nf = 0; nf < 4; ++nf) {
    int n = bn + wc * 64 + nf * 16 + lo;
    float bv = bias[n];
    int d = (int)((unsigned)n / 3u);
    int ch = n - d * 3;
    int h = d >> 6, hd = d & 63;
#pragma unroll
    for (int mf = 0; mf < 4; ++mf) {
      f32x4 a = acc[mf][nf];
#pragma unroll
      for (int j = 0; j < 4; ++j) {
        int m = bm + wr * 64 + mf * 16 + hi * 4 + j;
        int b_ = m >> 11, s = m & 2047;
        int bh = (b_ << 5) + h;
        float v = a[j] + bv;
        if (ch == 0)
          Qb[(bh * 2048 + s) * 64 + hd] = f2bf(v * (0.125f * 1.44269504f));
        else if (ch == 1)
          VT[(bh * 64 + hd) * 2048 + s] = f2bf(v);
        else
          Kb[(bh * 2048 + s) * 64 + hd] = f2bf(v);
      }
    }
  }
}

// ---------------- Pass 2: causal flash attention, split-KV ------------------
// grid = 64 bh * 64 qtiles (32 q-rows each); the 4 waves of a block split the
// kv chunks (c % 4 == w), each with private online softmax; partials merged
// through LDS. Swapped QK^T / PV on 32x32x16 MFMA, softmax in-register.
__global__ __launch_bounds__(256, 3) void attn(
    const ushort_t* __restrict__ Qb, const ushort_t* __restrict__ Kb,
    const ushort_t* __restrict__ VT, float* __restrict__ out) {
  __shared__ float LO[4][32 * 66];  // [wave][q*66 + hd] unnormalized partial O
  __shared__ float Lm[4][32];       // per-wave running max (log2 domain)
  __shared__ float Ll[4][32];       // per-wave running denom
  const int t = threadIdx.x;
  const int w = t >> 6, l = t & 63;
  const int ql = l & 31, hi = l >> 5;

  int bid = blockIdx.x;
  int swz = (bid & 7) * 512 + (bid >> 3);  // bijective XCD swizzle (4096=8*512)
  const int bh = swz >> 6;
  const int qt = 63 - (swz & 63);  // deepest q-tiles dispatch first
  const int q0 = qt * 32;
  const int nch = qt + 1;  // causal: kv chunks 0..qt

  // Q fragments (B operand): lane: col q = ql, k = d = dc*16 + hi*8 + j
  const ushort_t* qp = Qb + (bh * 2048 + q0 + ql) * 64 + hi * 8;
  bf16x8 qf[4];
#pragma unroll
  for (int dc = 0; dc < 4; ++dc) qf[dc] = ld_bf8(qp + dc * 16);

  f32x16 o0, o1;
#pragma unroll
  for (int r = 0; r < 16; ++r) { o0[r] = 0.f; o1[r] = 0.f; }
  float mr = -1e30f, lr = 0.f;

  const ushort_t* kbase = Kb + bh * 2048 * 64 + hi * 8;
  const ushort_t* vbase = VT + (bh * 64 + ql) * 2048 + hi * 8;

  // preload K fragments for this wave's first chunk
  bf16x8 kf[4];
  if (w < nch) {
    const ushort_t* kp = kbase + (w * 32 + ql) * 64;
#pragma unroll
    for (int dc = 0; dc < 4; ++dc) kf[dc] = ld_bf8(kp + dc * 16);
  }

  for (int c = w; c < nch; c += 4) {
    const int kb = c << 5;
    // prefetch next K chunk for this wave (clamped to a valid address)
    const int cn = (c + 4 < nch) ? (c + 4) : c;
    const ushort_t* kpn = kbase + (cn * 32 + ql) * 64;
    bf16x8 kn[4];
#pragma unroll
    for (int dc = 0; dc < 4; ++dc) kn[dc] = ld_bf8(kpn + dc * 16);
    // V fragments for this chunk
    bf16x8 vf0[2], vf1[2];
#pragma unroll
    for (int s = 0; s < 2; ++s) {
      const ushort_t* vp = vbase + kb + s * 16;
      vf0[s] = ld_bf8(vp);
      vf1[s] = ld_bf8(vp + 32 * 2048);
    }

    f32x16 p;
#pragma unroll
    for (int r = 0; r < 16; ++r) p[r] = 0.f;
    __builtin_amdgcn_s_setprio(1);
#pragma unroll
    for (int dc = 0; dc < 4; ++dc)
      p = __builtin_amdgcn_mfma_f32_32x32x16_bf16(kf[dc], qf[dc], p, 0, 0, 0);
    __builtin_amdgcn_s_setprio(0);
    // p[r] = S^T[kv = (r&3)+8*(r>>2)+4*hi][q = ql]  (log2-domain scores)
    if (c == nch - 1) {  // diagonal chunk: mask kv > q
#pragma unroll
      for (int r = 0; r < 16; ++r) {
        int kvr = (r & 3) + 8 * (r >> 2) + 4 * hi;
        if (kvr > ql) p[r] = -1e30f;
      }
    }
    float mx = p[0];
#pragma unroll
    for (int r = 1; r < 16; ++r) mx = fmaxf(mx, p[r]);
    mx = fmaxf(mx, __shfl_xor(mx, 32));
    float mn = fmaxf(mr, mx);
    float scl = ex2(mr - mn);
    mr = mn;
    float sum = 0.f;
#pragma unroll
    for (int r = 0; r < 16; ++r) {
      p[r] = ex2(p[r] - mn);
      sum += p[r];
    }
    sum += __shfl_xor(sum, 32);
    lr = lr * scl + sum;
#pragma unroll
    for (int r = 0; r < 16; ++r) { o0[r] *= scl; o1[r] *= scl; }

    // P^T -> bf16 B-fragments, in-register (cvt_pk + lane^32 exchange)
    __builtin_amdgcn_s_setprio(1);
#pragma unroll
    for (int s = 0; s < 2; ++s) {
      int x0 = cvtpk(p[8 * s + 0], p[8 * s + 1]);
      int x1 = cvtpk(p[8 * s + 2], p[8 * s + 3]);
      int y0 = cvtpk(p[8 * s + 4], p[8 * s + 5]);
      int y1 = cvtpk(p[8 * s + 6], p[8 * s + 7]);
      int ox0 = __shfl_xor(x0, 32);
      int ox1 = __shfl_xor(x1, 32);
      int oy0 = __shfl_xor(y0, 32);
      int oy1 = __shfl_xor(y1, 32);
      int4v wv;
      wv[0] = hi ? oy0 : x0;
      wv[1] = hi ? oy1 : x1;
      wv[2] = hi ? y0 : ox0;
      wv[3] = hi ? y1 : ox1;
      bf16x8 pf = __builtin_bit_cast(bf16x8, wv);
      o0 = __builtin_amdgcn_mfma_f32_32x32x16_bf16(vf0[s], pf, o0, 0, 0, 0);
      o1 = __builtin_amdgcn_mfma_f32_32x32x16_bf16(vf1[s], pf, o1, 0, 0, 0);
    }
    __builtin_amdgcn_s_setprio(0);
#pragma unroll
    for (int dc = 0; dc < 4; ++dc) kf[dc] = kn[dc];
  }

  // write this wave's partial (waves with no chunks write zeros / -1e30)
#pragma unroll
  for (int r = 0; r < 16; ++r) {
    int hdv = (r & 3) + 8 * (r >> 2) + 4 * hi;
    LO[w][ql * 66 + hdv] = o0[r];
    LO[w][ql * 66 + 32 + hdv] = o1[r];
  }
  if (hi == 0) {
    Lm[w][ql] = mr;
    Ll[w][ql] = lr;
  }
  __syncthreads();

  // merge: wave w finalizes q-rows w*8 .. w*8+7; lane l = hd
  const int b_ = bh >> 5, h = bh & 31;
#pragma unroll
  for (int ii = 0; ii < 8; ++ii) {
    int qi = w * 8 + ii;
    float m0 = Lm[0][qi], m1 = Lm[1][qi], m2 = Lm[2][qi], m3 = Lm[3][qi];
    float M = fmaxf(fmaxf(m0, m1), fmaxf(m2, m3));
    float w0 = ex2(m0 - M), w1 = ex2(m1 - M), w2 = ex2(m2 - M),
          w3 = ex2(m3 - M);
    float lsum = w0 * Ll[0][qi] + w1 * Ll[1][qi] + w2 * Ll[2][qi] +
                 w3 * Ll[3][qi];
    float acc = w0 * LO[0][qi * 66 + l] + w1 * LO[1][qi * 66 + l] +
                w2 * LO[2][qi * 66 + l] + w3 * LO[3][qi * 66 + l];
    out[(size_t)(b_ * 2048 + q0 + qi) * 2048 + h * 64 + l] = acc / lsum;
  }
}

// ---------------------------------------------------------------------------
extern "C" void kernel_launch(void* const* d_in, const int* in_sizes, int n_in,
                              void* d_out, int out_size, void* d_ws,
                              size_t ws_size, hipStream_t stream) {
  (void)in_sizes; (void)n_in; (void)out_size; (void)ws_size;
  const float* hs = (const float*)d_in[0];    // [2,2048,2048]
  const float* W = (const float*)d_in[1];     // [2048,6144]
  const float* bias = (const float*)d_in[2];  // [6144]
  float* out = (float*)d_out;

  char* ws = (char*)d_ws;
  ushort_t* Abf = (ushort_t*)(ws);                        // 16 MiB  [4096][2048]
  ushort_t* Wt = (ushort_t*)(ws + (16u << 20));           // 24 MiB  [6144][2048]
  ushort_t* Qb = (ushort_t*)(ws + (40u << 20));           // 16 MiB  [64][2048][64]
  ushort_t* Kb = (ushort_t*)(ws + (56u << 20));           // 16 MiB  [64][2048][64]
  ushort_t* VT = (ushort_t*)(ws + (72u << 20));           // 16 MiB  [64][64][2048]

  hipLaunchKernelGGL(cvt_hs, dim3(4096), dim3(256), 0, stream, hs, Abf);
  hipLaunchKernelGGL(transpose_W, dim3(3072), dim3(256), 0, stream, W, Wt);
  hipLaunchKernelGGL(gemm_qkv, dim3(1536), dim3(256), 0, stream, Abf, Wt, bias,
                     Qb, Kb, VT);
  hipLaunchKernelGGL(attn, dim3(4096), dim3(256), 0, stream, Qb, Kb, VT, out);
}

// Round 5
// 298.498 us; speedup vs baseline: 2.0321x; 1.0641x over previous
//
#include <hip/hip_runtime.h>
#include <hip/hip_bf16.h>
#include <stdint.h>

// Problem constants: B=2, S=2048, D=2048, H=32, HD=64, 3D=6144, M=B*S=4096, K=2048
typedef unsigned short ushort_t;
typedef __bf16 bf16x8 __attribute__((ext_vector_type(8)));
typedef float f32x4 __attribute__((ext_vector_type(4)));
typedef float f32x16 __attribute__((ext_vector_type(16)));
typedef int int4v __attribute__((ext_vector_type(4)));
typedef ushort_t ushort8 __attribute__((ext_vector_type(8)));

__device__ __forceinline__ ushort_t f2bf(float f) {
  union { float f; unsigned int u; } v; v.f = f;
  unsigned int r = v.u + 0x7fffu + ((v.u >> 16) & 1u);  // RNE
  return (ushort_t)(r >> 16);
}

__device__ __forceinline__ bf16x8 ld_bf8(const ushort_t* p) {
  return *reinterpret_cast<const bf16x8*>(p);
}

__device__ __forceinline__ void g2lds16(const void* g, void* l) {
  __builtin_amdgcn_global_load_lds(
      (const __attribute__((address_space(1))) unsigned int*)g,
      (__attribute__((address_space(3))) unsigned int*)l,
      16, 0, 0);
}

__device__ __forceinline__ float ex2(float x) { return __builtin_amdgcn_exp2f(x); }

// v_cvt_pk_bf16_f32: word = {lo: bf16(a), hi: bf16(b)}
__device__ __forceinline__ int cvtpk(float a, float b) {
  int r;
  asm("v_cvt_pk_bf16_f32 %0, %1, %2" : "=v"(r) : "v"(a), "v"(b));
  return r;
}

// ---------------- Pass 0a: hidden_states f32 -> bf16 (same layout) ----------
__global__ __launch_bounds__(256) void cvt_hs(const float* __restrict__ in,
                                              ushort_t* __restrict__ out) {
  int i = (blockIdx.x * 256 + threadIdx.x) * 8;
  float4 a = *reinterpret_cast<const float4*>(in + i);
  float4 b = *reinterpret_cast<const float4*>(in + i + 4);
  ushort8 r;
  r[0] = f2bf(a.x); r[1] = f2bf(a.y); r[2] = f2bf(a.z); r[3] = f2bf(a.w);
  r[4] = f2bf(b.x); r[5] = f2bf(b.y); r[6] = f2bf(b.z); r[7] = f2bf(b.w);
  *reinterpret_cast<ushort8*>(out + i) = r;
}

// ---------------- Pass 0b: W [2048][6144] f32 -> Wt [6144][2048] bf16 -------
__global__ __launch_bounds__(256) void transpose_W(const float* __restrict__ Win,
                                                   ushort_t* __restrict__ Wt) {
  __shared__ ushort_t T[64][65];
  const int t = threadIdx.x;
  const int k0 = (blockIdx.x & 31) * 64;
  const int n0 = (blockIdx.x >> 5) * 64;
#pragma unroll
  for (int i = 0; i < 16; ++i) {
    int idx = i * 256 + t;
    int r = idx >> 6, c = idx & 63;
    T[r][c] = f2bf(Win[(k0 + r) * 6144 + n0 + c]);
  }
  __syncthreads();
#pragma unroll
  for (int i = 0; i < 16; ++i) {
    int idx = i * 256 + t;
    int nr = idx >> 6, kc = idx & 63;
    Wt[(n0 + nr) * 2048 + k0 + kc] = T[kc][nr];
  }
}

// ---------------- Pass 1: QKV GEMM, head-aligned BN=192 ---------------------
// Tile 128m x 192n (= one head's q,v,k interleaved columns). Waves 2x2, each
// 64m x 96n (4x6 frags). Epilogue repacks through LDS for coalesced stores.
// Q pre-scaled by 0.125*log2(e) so attention can use exp2 directly.
__global__ __launch_bounds__(256, 2) void gemm_qkv(
    const ushort_t* __restrict__ A, const ushort_t* __restrict__ Bt,
    const float* __restrict__ bias,
    ushort_t* __restrict__ Qb, ushort_t* __restrict__ Kb,
    ushort_t* __restrict__ VT) {
  __shared__ __align__(16) char smem[25600];
  ushort_t* As = (ushort_t*)smem;            // [128][32]
  ushort_t* Bs = (ushort_t*)(smem + 8192);   // [192][32]
  ushort_t* Cs = (ushort_t*)smem;            // [64][200] epilogue alias
  const int t = threadIdx.x;
  const int w = t >> 6, l = t & 63;
  const int lo = l & 15, hi = l >> 4;
  const int wr = w >> 1, wc = w & 1;

  int bid = blockIdx.x;
  int swz = (bid & 7) * 128 + (bid >> 3);  // bijective (1024 = 8*128)
  const int mt = swz & 31, nt = swz >> 5;  // 32 x 32 tiles
  const int bm = mt * 128;
  const int bn = nt * 192;

  f32x4 acc[4][6];
#pragma unroll
  for (int i = 0; i < 4; ++i)
#pragma unroll
    for (int j = 0; j < 6; ++j) acc[i][j] = f32x4{0.f, 0.f, 0.f, 0.f};

  const ushort_t* Ag = A + (size_t)bm * 2048;
  const ushort_t* Bg = Bt + (size_t)bn * 2048;

  for (int kk = 0; kk < 2048; kk += 32) {
#pragma unroll
    for (int r2 = 0; r2 < 2; ++r2) {  // A: 128 rows x 32 cols
      int c = r2 * 256 + t;
      int row = c >> 2, s4 = c & 3;
      int slot = s4 ^ (row & 3);
      g2lds16(Ag + row * 2048 + kk + slot * 8, As + c * 8);
    }
#pragma unroll
    for (int r3 = 0; r3 < 3; ++r3) {  // B: 192 rows x 32 cols
      int c = r3 * 256 + t;
      int row = c >> 2, s4 = c & 3;
      int slot = s4 ^ (row & 3);
      g2lds16(Bg + row * 2048 + kk + slot * 8, Bs + c * 8);
    }
    __syncthreads();
    bf16x8 af[4], bfr[6];
#pragma unroll
    for (int mf = 0; mf < 4; ++mf) {
      int row = wr * 64 + mf * 16 + lo;
      af[mf] = ld_bf8(As + row * 32 + ((hi ^ (row & 3)) << 3));
    }
#pragma unroll
    for (int nf = 0; nf < 6; ++nf) {
      int row = wc * 96 + nf * 16 + lo;
      bfr[nf] = ld_bf8(Bs + row * 32 + ((hi ^ (row & 3)) << 3));
    }
    __builtin_amdgcn_s_setprio(1);
#pragma unroll
    for (int mf = 0; mf < 4; ++mf)
#pragma unroll
      for (int nf = 0; nf < 6; ++nf)
        acc[mf][nf] = __builtin_amdgcn_mfma_f32_16x16x32_bf16(
            af[mf], bfr[nf], acc[mf][nf], 0, 0, 0);
    __builtin_amdgcn_s_setprio(0);
    __syncthreads();
  }

  // ---- epilogue: bias + de-interleave via LDS repack, coalesced stores ----
  float bv[6];
  int ch[6];
#pragma unroll
  for (int nf = 0; nf < 6; ++nf) {
    int nl = wc * 96 + nf * 16 + lo;
    bv[nf] = bias[bn + nl];
    ch[nf] = nl % 3;
  }
  const int b_ = bm >> 11;
  const int bh = (b_ << 5) + nt;  // head index == nt
  const float QS = 0.125f * 1.44269504f;

#pragma unroll
  for (int h = 0; h < 2; ++h) {
    if (wr == h) {
#pragma unroll
      for (int mf = 0; mf < 4; ++mf)
#pragma unroll
        for (int nf = 0; nf < 6; ++nf) {
          int rloc = mf * 16 + hi * 4;
          int nl = wc * 96 + nf * 16 + lo;
          f32x4 a = acc[mf][nf];
#pragma unroll
          for (int j = 0; j < 4; ++j) {
            float v = a[j] + bv[nf];
            if (ch[nf] == 0) v *= QS;
            Cs[(rloc + j) * 200 + nl] = f2bf(v);
          }
        }
    }
    __syncthreads();
    const int sbase = (bm & 2047) + h * 64;
    // Q (ch0: nl = 3*hd) and K (ch2: nl = 3*hd+2): row-contiguous 16B stores
#pragma unroll
    for (int it = 0; it < 2; ++it) {
      int slot = it * 256 + t;
      int r = slot >> 3, g = slot & 7;
      ushort8 vq, vk;
#pragma unroll
      for (int u = 0; u < 8; ++u) {
        int hd = g * 8 + u;
        vq[u] = Cs[r * 200 + hd * 3];
        vk[u] = Cs[r * 200 + hd * 3 + 2];
      }
      size_t rowoff = ((size_t)bh * 2048 + sbase + r) * 64 + g * 8;
      *reinterpret_cast<ushort8*>(Qb + rowoff) = vq;
      *reinterpret_cast<ushort8*>(Kb + rowoff) = vk;
    }
    // V (ch1: nl = 3*hd+1) -> VT[bh][hd][s]: 16B runs along s
#pragma unroll
    for (int it = 0; it < 2; ++it) {
      int slot = it * 256 + t;
      int hd = slot >> 3, sg = slot & 7;
      ushort8 vv;
#pragma unroll
      for (int u = 0; u < 8; ++u) vv[u] = Cs[(sg * 8 + u) * 200 + hd * 3 + 1];
      *reinterpret_cast<ushort8*>(VT + ((size_t)bh * 64 + hd) * 2048 + sbase +
                                  sg * 8) = vv;
    }
    __syncthreads();
  }
}

// ---------------- Pass 2: causal flash attention, split-KV ------------------
// grid = 64 bh * 64 qtiles (32 q-rows each); the 4 waves of a block split the
// kv chunks (c % 4 == w), each with private online softmax; partials merged
// through LDS. Swapped QK^T / PV on 32x32x16 MFMA, softmax in-register.
// (Softmax sequence is the R3-verified one: shfl_xor(32) + always-rescale.)
__global__ __launch_bounds__(256, 4) void attn(
    const ushort_t* __restrict__ Qb, const ushort_t* __restrict__ Kb,
    const ushort_t* __restrict__ VT, float* __restrict__ out) {
  __shared__ float LO[4][32 * 66];
  __shared__ float Lm[4][32];
  __shared__ float Ll[4][32];
  const int t = threadIdx.x;
  const int w = t >> 6, l = t & 63;
  const int ql = l & 31, hi = l >> 5;

  int bid = blockIdx.x;
  int swz = (bid & 7) * 512 + (bid >> 3);  // bijective (4096 = 8*512)
  const int bh = swz >> 6;
  const int qt = 63 - (swz & 63);  // deepest q-tiles dispatch first
  const int q0 = qt * 32;
  const int nch = qt + 1;

  const ushort_t* qp = Qb + (bh * 2048 + q0 + ql) * 64 + hi * 8;
  bf16x8 qf[4];
#pragma unroll
  for (int dc = 0; dc < 4; ++dc) qf[dc] = ld_bf8(qp + dc * 16);

  f32x16 o0, o1;
#pragma unroll
  for (int r = 0; r < 16; ++r) { o0[r] = 0.f; o1[r] = 0.f; }
  float mr = -1e30f, lr = 0.f;

  const ushort_t* kbase = Kb + bh * 2048 * 64 + hi * 8;
  const ushort_t* vbase = VT + (bh * 64 + ql) * 2048 + hi * 8;

  bf16x8 kf[4];
  if (w < nch) {
    const ushort_t* kp = kbase + (w * 32 + ql) * 64;
#pragma unroll
    for (int dc = 0; dc < 4; ++dc) kf[dc] = ld_bf8(kp + dc * 16);
  }

  for (int c = w; c < nch; c += 4) {
    const int kb = c << 5;
    const int cn = (c + 4 < nch) ? (c + 4) : c;
    const ushort_t* kpn = kbase + (cn * 32 + ql) * 64;
    bf16x8 kn[4];
#pragma unroll
    for (int dc = 0; dc < 4; ++dc) kn[dc] = ld_bf8(kpn + dc * 16);
    bf16x8 vf0[2], vf1[2];
#pragma unroll
    for (int s = 0; s < 2; ++s) {
      const ushort_t* vp = vbase + kb + s * 16;
      vf0[s] = ld_bf8(vp);
      vf1[s] = ld_bf8(vp + 32 * 2048);
    }

    f32x16 p;
#pragma unroll
    for (int r = 0; r < 16; ++r) p[r] = 0.f;
    __builtin_amdgcn_s_setprio(1);
#pragma unroll
    for (int dc = 0; dc < 4; ++dc)
      p = __builtin_amdgcn_mfma_f32_32x32x16_bf16(kf[dc], qf[dc], p, 0, 0, 0);
    __builtin_amdgcn_s_setprio(0);
    if (c == nch - 1) {  // diagonal chunk: mask kv > q
#pragma unroll
      for (int r = 0; r < 16; ++r) {
        int kvr = (r & 3) + 8 * (r >> 2) + 4 * hi;
        if (kvr > ql) p[r] = -1e30f;
      }
    }
    float mx = p[0];
#pragma unroll
    for (int r = 1; r < 16; ++r) mx = fmaxf(mx, p[r]);
    mx = fmaxf(mx, __shfl_xor(mx, 32));
    float mn = fmaxf(mr, mx);
    float scl = ex2(mr - mn);
    mr = mn;
    float sum = 0.f;
#pragma unroll
    for (int r = 0; r < 16; ++r) {
      p[r] = ex2(p[r] - mn);
      sum += p[r];
    }
    sum += __shfl_xor(sum, 32);
    lr = lr * scl + sum;
#pragma unroll
    for (int r = 0; r < 16; ++r) { o0[r] *= scl; o1[r] *= scl; }

    // P^T -> bf16 B-fragments, in-register (cvt_pk + lane^32 exchange)
    __builtin_amdgcn_s_setprio(1);
#pragma unroll
    for (int s = 0; s < 2; ++s) {
      int x0 = cvtpk(p[8 * s + 0], p[8 * s + 1]);
      int x1 = cvtpk(p[8 * s + 2], p[8 * s + 3]);
      int y0 = cvtpk(p[8 * s + 4], p[8 * s + 5]);
      int y1 = cvtpk(p[8 * s + 6], p[8 * s + 7]);
      int ox0 = __shfl_xor(x0, 32);
      int ox1 = __shfl_xor(x1, 32);
      int oy0 = __shfl_xor(y0, 32);
      int oy1 = __shfl_xor(y1, 32);
      int4v wv;
      wv[0] = hi ? oy0 : x0;
      wv[1] = hi ? oy1 : x1;
      wv[2] = hi ? y0 : ox0;
      wv[3] = hi ? y1 : ox1;
      bf16x8 pf = __builtin_bit_cast(bf16x8, wv);
      o0 = __builtin_amdgcn_mfma_f32_32x32x16_bf16(vf0[s], pf, o0, 0, 0, 0);
      o1 = __builtin_amdgcn_mfma_f32_32x32x16_bf16(vf1[s], pf, o1, 0, 0, 0);
    }
    __builtin_amdgcn_s_setprio(0);
#pragma unroll
    for (int dc = 0; dc < 4; ++dc) kf[dc] = kn[dc];
  }

#pragma unroll
  for (int r = 0; r < 16; ++r) {
    int hdv = (r & 3) + 8 * (r >> 2) + 4 * hi;
    LO[w][ql * 66 + hdv] = o0[r];
    LO[w][ql * 66 + 32 + hdv] = o1[r];
  }
  if (hi == 0) {
    Lm[w][ql] = mr;
    Ll[w][ql] = lr;
  }
  __syncthreads();

  const int b_ = bh >> 5, h = bh & 31;
#pragma unroll
  for (int ii = 0; ii < 8; ++ii) {
    int qi = w * 8 + ii;
    float m0 = Lm[0][qi], m1 = Lm[1][qi], m2 = Lm[2][qi], m3 = Lm[3][qi];
    float M = fmaxf(fmaxf(m0, m1), fmaxf(m2, m3));
    float w0 = ex2(m0 - M), w1 = ex2(m1 - M), w2 = ex2(m2 - M),
          w3 = ex2(m3 - M);
    float lsum = w0 * Ll[0][qi] + w1 * Ll[1][qi] + w2 * Ll[2][qi] +
                 w3 * Ll[3][qi];
    float acc = w0 * LO[0][qi * 66 + l] + w1 * LO[1][qi * 66 + l] +
                w2 * LO[2][qi * 66 + l] + w3 * LO[3][qi * 66 + l];
    out[(size_t)(b_ * 2048 + q0 + qi) * 2048 + h * 64 + l] = acc / lsum;
  }
}

// ---------------------------------------------------------------------------
extern "C" void kernel_launch(void* const* d_in, const int* in_sizes, int n_in,
                              void* d_out, int out_size, void* d_ws,
                              size_t ws_size, hipStream_t stream) {
  (void)in_sizes; (void)n_in; (void)out_size; (void)ws_size;
  const float* hs = (const float*)d_in[0];    // [2,2048,2048]
  const float* W = (const float*)d_in[1];     // [2048,6144]
  const float* bias = (const float*)d_in[2];  // [6144]
  float* out = (float*)d_out;

  char* ws = (char*)d_ws;
  ushort_t* Abf = (ushort_t*)(ws);                        // 16 MiB  [4096][2048]
  ushort_t* Wt = (ushort_t*)(ws + (16u << 20));           // 24 MiB  [6144][2048]
  ushort_t* Qb = (ushort_t*)(ws + (40u << 20));           // 16 MiB  [64][2048][64]
  ushort_t* Kb = (ushort_t*)(ws + (56u << 20));           // 16 MiB  [64][2048][64]
  ushort_t* VT = (ushort_t*)(ws + (72u << 20));           // 16 MiB  [64][64][2048]

  hipLaunchKernelGGL(cvt_hs, dim3(4096), dim3(256), 0, stream, hs, Abf);
  hipLaunchKernelGGL(transpose_W, dim3(3072), dim3(256), 0, stream, W, Wt);
  hipLaunchKernelGGL(gemm_qkv, dim3(1024), dim3(256), 0, stream, Abf, Wt, bias,
                     Qb, Kb, VT);
  hipLaunchKernelGGL(attn, dim3(4096), dim3(256), 0, stream, Qb, Kb, VT, out);
}

// Round 6
// 293.374 us; speedup vs baseline: 2.0676x; 1.0175x over previous
//
#include <hip/hip_runtime.h>
#include <hip/hip_bf16.h>
#include <stdint.h>

// Problem constants: B=2, S=2048, D=2048, H=32, HD=64, 3D=6144, M=B*S=4096, K=2048
typedef unsigned short ushort_t;
typedef __bf16 bf16x8 __attribute__((ext_vector_type(8)));
typedef float f32x4 __attribute__((ext_vector_type(4)));
typedef float f32x16 __attribute__((ext_vector_type(16)));
typedef int int4v __attribute__((ext_vector_type(4)));
typedef ushort_t ushort8 __attribute__((ext_vector_type(8)));

__device__ __forceinline__ ushort_t f2bf(float f) {
  union { float f; unsigned int u; } v; v.f = f;
  unsigned int r = v.u + 0x7fffu + ((v.u >> 16) & 1u);  // RNE
  return (ushort_t)(r >> 16);
}

__device__ __forceinline__ bf16x8 ld_bf8(const ushort_t* p) {
  return *reinterpret_cast<const bf16x8*>(p);
}

__device__ __forceinline__ void g2lds16(const void* g, void* l) {
  __builtin_amdgcn_global_load_lds(
      (const __attribute__((address_space(1))) unsigned int*)g,
      (__attribute__((address_space(3))) unsigned int*)l,
      16, 0, 0);
}

__device__ __forceinline__ float ex2(float x) { return __builtin_amdgcn_exp2f(x); }

// v_cvt_pk_bf16_f32: word = {lo: bf16(a), hi: bf16(b)}
__device__ __forceinline__ int cvtpk(float a, float b) {
  int r;
  asm("v_cvt_pk_bf16_f32 %0, %1, %2" : "=v"(r) : "v"(a), "v"(b));
  return r;
}

// ---------------- Pass 0a: hidden_states f32 -> bf16 (same layout) ----------
__global__ __launch_bounds__(256) void cvt_hs(const float* __restrict__ in,
                                              ushort_t* __restrict__ out) {
  int i = (blockIdx.x * 256 + threadIdx.x) * 8;
  float4 a = *reinterpret_cast<const float4*>(in + i);
  float4 b = *reinterpret_cast<const float4*>(in + i + 4);
  ushort8 r;
  r[0] = f2bf(a.x); r[1] = f2bf(a.y); r[2] = f2bf(a.z); r[3] = f2bf(a.w);
  r[4] = f2bf(b.x); r[5] = f2bf(b.y); r[6] = f2bf(b.z); r[7] = f2bf(b.w);
  *reinterpret_cast<ushort8*>(out + i) = r;
}

// ---------------- Pass 0b: W [2048][6144] f32 -> Wt [6144][2048] bf16 -------
__global__ __launch_bounds__(256) void transpose_W(const float* __restrict__ Win,
                                                   ushort_t* __restrict__ Wt) {
  __shared__ ushort_t T[64][65];
  const int t = threadIdx.x;
  const int k0 = (blockIdx.x & 31) * 64;
  const int n0 = (blockIdx.x >> 5) * 64;
#pragma unroll
  for (int i = 0; i < 16; ++i) {
    int idx = i * 256 + t;
    int r = idx >> 6, c = idx & 63;
    T[r][c] = f2bf(Win[(k0 + r) * 6144 + n0 + c]);
  }
  __syncthreads();
#pragma unroll
  for (int i = 0; i < 16; ++i) {
    int idx = i * 256 + t;
    int nr = idx >> 6, kc = idx & 63;
    Wt[(n0 + nr) * 2048 + k0 + kc] = T[kc][nr];
  }
}

// ---------------- Pass 1: QKV GEMM, head-aligned BN=192 ---------------------
// Tile 128m x 192n (= one head's q,v,k interleaved columns). Waves 2x2, each
// 64m x 96n (4x6 frags). Epilogue repacks through LDS for coalesced stores.
// Q pre-scaled by 0.125*log2(e) so attention can use exp2 directly.
__global__ __launch_bounds__(256, 2) void gemm_qkv(
    const ushort_t* __restrict__ A, const ushort_t* __restrict__ Bt,
    const float* __restrict__ bias,
    ushort_t* __restrict__ Qb, ushort_t* __restrict__ Kb,
    ushort_t* __restrict__ VT) {
  __shared__ __align__(16) char smem[25600];
  ushort_t* As = (ushort_t*)smem;            // [128][32]
  ushort_t* Bs = (ushort_t*)(smem + 8192);   // [192][32]
  ushort_t* Cs = (ushort_t*)smem;            // [64][200] epilogue alias
  const int t = threadIdx.x;
  const int w = t >> 6, l = t & 63;
  const int lo = l & 15, hi = l >> 4;
  const int wr = w >> 1, wc = w & 1;

  int bid = blockIdx.x;
  int swz = (bid & 7) * 128 + (bid >> 3);  // bijective (1024 = 8*128)
  const int mt = swz & 31, nt = swz >> 5;  // 32 x 32 tiles
  const int bm = mt * 128;
  const int bn = nt * 192;

  f32x4 acc[4][6];
#pragma unroll
  for (int i = 0; i < 4; ++i)
#pragma unroll
    for (int j = 0; j < 6; ++j) acc[i][j] = f32x4{0.f, 0.f, 0.f, 0.f};

  const ushort_t* Ag = A + (size_t)bm * 2048;
  const ushort_t* Bg = Bt + (size_t)bn * 2048;

  for (int kk = 0; kk < 2048; kk += 32) {
#pragma unroll
    for (int r2 = 0; r2 < 2; ++r2) {  // A: 128 rows x 32 cols
      int c = r2 * 256 + t;
      int row = c >> 2, s4 = c & 3;
      int slot = s4 ^ (row & 3);
      g2lds16(Ag + row * 2048 + kk + slot * 8, As + c * 8);
    }
#pragma unroll
    for (int r3 = 0; r3 < 3; ++r3) {  // B: 192 rows x 32 cols
      int c = r3 * 256 + t;
      int row = c >> 2, s4 = c & 3;
      int slot = s4 ^ (row & 3);
      g2lds16(Bg + row * 2048 + kk + slot * 8, Bs + c * 8);
    }
    __syncthreads();
    bf16x8 af[4], bfr[6];
#pragma unroll
    for (int mf = 0; mf < 4; ++mf) {
      int row = wr * 64 + mf * 16 + lo;
      af[mf] = ld_bf8(As + row * 32 + ((hi ^ (row & 3)) << 3));
    }
#pragma unroll
    for (int nf = 0; nf < 6; ++nf) {
      int row = wc * 96 + nf * 16 + lo;
      bfr[nf] = ld_bf8(Bs + row * 32 + ((hi ^ (row & 3)) << 3));
    }
    __builtin_amdgcn_s_setprio(1);
#pragma unroll
    for (int mf = 0; mf < 4; ++mf)
#pragma unroll
      for (int nf = 0; nf < 6; ++nf)
        acc[mf][nf] = __builtin_amdgcn_mfma_f32_16x16x32_bf16(
            af[mf], bfr[nf], acc[mf][nf], 0, 0, 0);
    __builtin_amdgcn_s_setprio(0);
    __syncthreads();
  }

  // ---- epilogue: bias + de-interleave via LDS repack, coalesced stores ----
  float bv[6];
  int ch[6];
#pragma unroll
  for (int nf = 0; nf < 6; ++nf) {
    int nl = wc * 96 + nf * 16 + lo;
    bv[nf] = bias[bn + nl];
    ch[nf] = nl % 3;
  }
  const int b_ = bm >> 11;
  const int bh = (b_ << 5) + nt;  // head index == nt
  const float QS = 0.125f * 1.44269504f;

#pragma unroll
  for (int h = 0; h < 2; ++h) {
    if (wr == h) {
#pragma unroll
      for (int mf = 0; mf < 4; ++mf)
#pragma unroll
        for (int nf = 0; nf < 6; ++nf) {
          int rloc = mf * 16 + hi * 4;
          int nl = wc * 96 + nf * 16 + lo;
          f32x4 a = acc[mf][nf];
#pragma unroll
          for (int j = 0; j < 4; ++j) {
            float v = a[j] + bv[nf];
            if (ch[nf] == 0) v *= QS;
            Cs[(rloc + j) * 200 + nl] = f2bf(v);
          }
        }
    }
    __syncthreads();
    const int sbase = (bm & 2047) + h * 64;
    // Q (ch0: nl = 3*hd) and K (ch2: nl = 3*hd+2): row-contiguous 16B stores
#pragma unroll
    for (int it = 0; it < 2; ++it) {
      int slot = it * 256 + t;
      int r = slot >> 3, g = slot & 7;
      ushort8 vq, vk;
#pragma unroll
      for (int u = 0; u < 8; ++u) {
        int hd = g * 8 + u;
        vq[u] = Cs[r * 200 + hd * 3];
        vk[u] = Cs[r * 200 + hd * 3 + 2];
      }
      size_t rowoff = ((size_t)bh * 2048 + sbase + r) * 64 + g * 8;
      *reinterpret_cast<ushort8*>(Qb + rowoff) = vq;
      *reinterpret_cast<ushort8*>(Kb + rowoff) = vk;
    }
    // V (ch1: nl = 3*hd+1) -> VT[bh][hd][s]: 16B runs along s
#pragma unroll
    for (int it = 0; it < 2; ++it) {
      int slot = it * 256 + t;
      int hd = slot >> 3, sg = slot & 7;
      ushort8 vv;
#pragma unroll
      for (int u = 0; u < 8; ++u) vv[u] = Cs[(sg * 8 + u) * 200 + hd * 3 + 1];
      *reinterpret_cast<ushort8*>(VT + ((size_t)bh * 64 + hd) * 2048 + sbase +
                                  sg * 8) = vv;
    }
    __syncthreads();
  }
}

// ---------------- Pass 2: causal flash attention, 1 wave / q-tile -----------
// grid = 4096 one-wave blocks; block = (bh, 32-row q-tile), fully independent:
// no barriers in the main loop, no cross-wave merge. Per-chunk math is the
// R3/R5-verified sequence (swapped QK^T / PV on 32x32x16, shfl_xor(32)
// softmax, always-rescale, cvtpk repack). Epilogue: wave-private LDS
// detranspose -> coalesced 256B row stores.
__global__ __launch_bounds__(64) void attn(
    const ushort_t* __restrict__ Qb, const ushort_t* __restrict__ Kb,
    const ushort_t* __restrict__ VT, float* __restrict__ out) {
  __shared__ float Ld[32 * 66];  // 8448 B, wave-private
  const int l = threadIdx.x;
  const int ql = l & 31, hi = l >> 5;

  int bid = blockIdx.x;
  int swz = (bid & 7) * 512 + (bid >> 3);  // bijective (4096 = 8*512)
  const int bh = swz >> 6;                 // 8 bh per XCD (K/V = 4MB = L2)
  const int qt = 63 - (swz & 63);          // deepest q-tiles dispatch first
  const int q0 = qt * 32;
  const int nch = qt + 1;

  const ushort_t* qp = Qb + (bh * 2048 + q0 + ql) * 64 + hi * 8;
  bf16x8 qf[4];
#pragma unroll
  for (int dc = 0; dc < 4; ++dc) qf[dc] = ld_bf8(qp + dc * 16);

  f32x16 o0, o1;
#pragma unroll
  for (int r = 0; r < 16; ++r) { o0[r] = 0.f; o1[r] = 0.f; }
  float mr = -1e30f, lr = 0.f;

  const ushort_t* kbase = Kb + bh * 2048 * 64 + hi * 8;
  const ushort_t* vbase = VT + (bh * 64 + ql) * 2048 + hi * 8;

  bf16x8 kf[4];
  {
    const ushort_t* kp = kbase + ql * 64;  // chunk 0
#pragma unroll
    for (int dc = 0; dc < 4; ++dc) kf[dc] = ld_bf8(kp + dc * 16);
  }

  for (int c = 0; c < nch; ++c) {
    const int kb = c << 5;
    const int cn = (c + 1 < nch) ? (c + 1) : c;
    const ushort_t* kpn = kbase + (cn * 32 + ql) * 64;
    bf16x8 kn[4];
#pragma unroll
    for (int dc = 0; dc < 4; ++dc) kn[dc] = ld_bf8(kpn + dc * 16);
    bf16x8 vf0[2], vf1[2];
#pragma unroll
    for (int s = 0; s < 2; ++s) {
      const ushort_t* vp = vbase + kb + s * 16;
      vf0[s] = ld_bf8(vp);
      vf1[s] = ld_bf8(vp + 32 * 2048);
    }

    f32x16 p;
#pragma unroll
    for (int r = 0; r < 16; ++r) p[r] = 0.f;
    __builtin_amdgcn_s_setprio(1);
#pragma unroll
    for (int dc = 0; dc < 4; ++dc)
      p = __builtin_amdgcn_mfma_f32_32x32x16_bf16(kf[dc], qf[dc], p, 0, 0, 0);
    __builtin_amdgcn_s_setprio(0);
    if (c == nch - 1) {  // diagonal chunk: mask kv > q
#pragma unroll
      for (int r = 0; r < 16; ++r) {
        int kvr = (r & 3) + 8 * (r >> 2) + 4 * hi;
        if (kvr > ql) p[r] = -1e30f;
      }
    }
    float mx = p[0];
#pragma unroll
    for (int r = 1; r < 16; ++r) mx = fmaxf(mx, p[r]);
    mx = fmaxf(mx, __shfl_xor(mx, 32));
    float mn = fmaxf(mr, mx);
    float scl = ex2(mr - mn);
    mr = mn;
    float sum = 0.f;
#pragma unroll
    for (int r = 0; r < 16; ++r) {
      p[r] = ex2(p[r] - mn);
      sum += p[r];
    }
    sum += __shfl_xor(sum, 32);
    lr = lr * scl + sum;
#pragma unroll
    for (int r = 0; r < 16; ++r) { o0[r] *= scl; o1[r] *= scl; }

    // P^T -> bf16 B-fragments, in-register (cvt_pk + lane^32 exchange)
    __builtin_amdgcn_s_setprio(1);
#pragma unroll
    for (int s = 0; s < 2; ++s) {
      int x0 = cvtpk(p[8 * s + 0], p[8 * s + 1]);
      int x1 = cvtpk(p[8 * s + 2], p[8 * s + 3]);
      int y0 = cvtpk(p[8 * s + 4], p[8 * s + 5]);
      int y1 = cvtpk(p[8 * s + 6], p[8 * s + 7]);
      int ox0 = __shfl_xor(x0, 32);
      int ox1 = __shfl_xor(x1, 32);
      int oy0 = __shfl_xor(y0, 32);
      int oy1 = __shfl_xor(y1, 32);
      int4v wv;
      wv[0] = hi ? oy0 : x0;
      wv[1] = hi ? oy1 : x1;
      wv[2] = hi ? y0 : ox0;
      wv[3] = hi ? y1 : ox1;
      bf16x8 pf = __builtin_bit_cast(bf16x8, wv);
      o0 = __builtin_amdgcn_mfma_f32_32x32x16_bf16(vf0[s], pf, o0, 0, 0, 0);
      o1 = __builtin_amdgcn_mfma_f32_32x32x16_bf16(vf1[s], pf, o1, 0, 0, 0);
    }
    __builtin_amdgcn_s_setprio(0);
#pragma unroll
    for (int dc = 0; dc < 4; ++dc) kf[dc] = kn[dc];
  }

  // epilogue: normalize, wave-private LDS detranspose, coalesced row stores
  const float inv = 1.0f / lr;
#pragma unroll
  for (int r = 0; r < 16; ++r) {
    int hdv = (r & 3) + 8 * (r >> 2) + 4 * hi;
    Ld[ql * 66 + hdv] = o0[r] * inv;
    Ld[ql * 66 + 32 + hdv] = o1[r] * inv;
  }
  __syncthreads();
  const int b_ = bh >> 5, h = bh & 31;
  float* op = out + (size_t)(b_ * 2048 + q0) * 2048 + h * 64 + l;
#pragma unroll
  for (int i = 0; i < 32; ++i) {
    op[(size_t)i * 2048] = Ld[i * 66 + l];
  }
}

// ---------------------------------------------------------------------------
extern "C" void kernel_launch(void* const* d_in, const int* in_sizes, int n_in,
                              void* d_out, int out_size, void* d_ws,
                              size_t ws_size, hipStream_t stream) {
  (void)in_sizes; (void)n_in; (void)out_size; (void)ws_size;
  const float* hs = (const float*)d_in[0];    // [2,2048,2048]
  const float* W = (const float*)d_in[1];     // [2048,6144]
  const float* bias = (const float*)d_in[2];  // [6144]
  float* out = (float*)d_out;

  char* ws = (char*)d_ws;
  ushort_t* Abf = (ushort_t*)(ws);                        // 16 MiB  [4096][2048]
  ushort_t* Wt = (ushort_t*)(ws + (16u << 20));           // 24 MiB  [6144][2048]
  ushort_t* Qb = (ushort_t*)(ws + (40u << 20));           // 16 MiB  [64][2048][64]
  ushort_t* Kb = (ushort_t*)(ws + (56u << 20));           // 16 MiB  [64][2048][64]
  ushort_t* VT = (ushort_t*)(ws + (72u << 20));           // 16 MiB  [64][64][2048]

  hipLaunchKernelGGL(cvt_hs, dim3(4096), dim3(256), 0, stream, hs, Abf);
  hipLaunchKernelGGL(transpose_W, dim3(3072), dim3(256), 0, stream, W, Wt);
  hipLaunchKernelGGL(gemm_qkv, dim3(1024), dim3(256), 0, stream, Abf, Wt, bias,
                     Qb, Kb, VT);
  hipLaunchKernelGGL(attn, dim3(4096), dim3(64), 0, stream, Qb, Kb, VT, out);
}

// Round 7
// 271.921 us; speedup vs baseline: 2.2307x; 1.0789x over previous
//
#include <hip/hip_runtime.h>
#include <hip/hip_bf16.h>
#include <stdint.h>

// Problem constants: B=2, S=2048, D=2048, H=32, HD=64, 3D=6144, M=B*S=4096, K=2048
typedef unsigned short ushort_t;
typedef __bf16 bf16x8 __attribute__((ext_vector_type(8)));
typedef float f32x4 __attribute__((ext_vector_type(4)));
typedef float f32x16 __attribute__((ext_vector_type(16)));
typedef int int4v __attribute__((ext_vector_type(4)));
typedef ushort_t ushort8 __attribute__((ext_vector_type(8)));

__device__ __forceinline__ ushort_t f2bf(float f) {
  union { float f; unsigned int u; } v; v.f = f;
  unsigned int r = v.u + 0x7fffu + ((v.u >> 16) & 1u);  // RNE
  return (ushort_t)(r >> 16);
}

__device__ __forceinline__ bf16x8 ld_bf8(const ushort_t* p) {
  return *reinterpret_cast<const bf16x8*>(p);
}

__device__ __forceinline__ void g2lds16(const void* g, void* l) {
  __builtin_amdgcn_global_load_lds(
      (const __attribute__((address_space(1))) unsigned int*)g,
      (__attribute__((address_space(3))) unsigned int*)l,
      16, 0, 0);
}

__device__ __forceinline__ float ex2(float x) { return __builtin_amdgcn_exp2f(x); }

// v_cvt_pk_bf16_f32: word = {lo: bf16(a), hi: bf16(b)}
__device__ __forceinline__ int cvtpk(float a, float b) {
  int r;
  asm("v_cvt_pk_bf16_f32 %0, %1, %2" : "=v"(r) : "v"(a), "v"(b));
  return r;
}

// ---------------- Pass 0a: hidden_states f32 -> bf16 (same layout) ----------
__global__ __launch_bounds__(256) void cvt_hs(const float* __restrict__ in,
                                              ushort_t* __restrict__ out) {
  int i = (blockIdx.x * 256 + threadIdx.x) * 8;
  float4 a = *reinterpret_cast<const float4*>(in + i);
  float4 b = *reinterpret_cast<const float4*>(in + i + 4);
  ushort8 r;
  r[0] = f2bf(a.x); r[1] = f2bf(a.y); r[2] = f2bf(a.z); r[3] = f2bf(a.w);
  r[4] = f2bf(b.x); r[5] = f2bf(b.y); r[6] = f2bf(b.z); r[7] = f2bf(b.w);
  *reinterpret_cast<ushort8*>(out + i) = r;
}

// ---------------- Pass 0b: W [2048][6144] f32 -> Wt [6144][2048] bf16 -------
__global__ __launch_bounds__(256) void transpose_W(const float* __restrict__ Win,
                                                   ushort_t* __restrict__ Wt) {
  __shared__ ushort_t T[64][65];
  const int t = threadIdx.x;
  const int k0 = (blockIdx.x & 31) * 64;
  const int n0 = (blockIdx.x >> 5) * 64;
#pragma unroll
  for (int i = 0; i < 16; ++i) {
    int idx = i * 256 + t;
    int r = idx >> 6, c = idx & 63;
    T[r][c] = f2bf(Win[(k0 + r) * 6144 + n0 + c]);
  }
  __syncthreads();
#pragma unroll
  for (int i = 0; i < 16; ++i) {
    int idx = i * 256 + t;
    int nr = idx >> 6, kc = idx & 63;
    Wt[(n0 + nr) * 2048 + k0 + kc] = T[kc][nr];
  }
}

// ---------------- Pass 1: QKV GEMM, head-aligned BN=192 ---------------------
// Tile 128m x 192n (= one head's q,v,k interleaved columns). Waves 2x2, each
// 64m x 96n (4x6 frags). Epilogue repacks through LDS for coalesced stores.
// Q pre-scaled by 0.125*log2(e) so attention can use exp2 directly.
__global__ __launch_bounds__(256, 2) void gemm_qkv(
    const ushort_t* __restrict__ A, const ushort_t* __restrict__ Bt,
    const float* __restrict__ bias,
    ushort_t* __restrict__ Qb, ushort_t* __restrict__ Kb,
    ushort_t* __restrict__ VT) {
  __shared__ __align__(16) char smem[25600];
  ushort_t* As = (ushort_t*)smem;            // [128][32]
  ushort_t* Bs = (ushort_t*)(smem + 8192);   // [192][32]
  ushort_t* Cs = (ushort_t*)smem;            // [64][200] epilogue alias
  const int t = threadIdx.x;
  const int w = t >> 6, l = t & 63;
  const int lo = l & 15, hi = l >> 4;
  const int wr = w >> 1, wc = w & 1;

  int bid = blockIdx.x;
  int swz = (bid & 7) * 128 + (bid >> 3);  // bijective (1024 = 8*128)
  const int mt = swz & 31, nt = swz >> 5;  // 32 x 32 tiles
  const int bm = mt * 128;
  const int bn = nt * 192;

  f32x4 acc[4][6];
#pragma unroll
  for (int i = 0; i < 4; ++i)
#pragma unroll
    for (int j = 0; j < 6; ++j) acc[i][j] = f32x4{0.f, 0.f, 0.f, 0.f};

  const ushort_t* Ag = A + (size_t)bm * 2048;
  const ushort_t* Bg = Bt + (size_t)bn * 2048;

  for (int kk = 0; kk < 2048; kk += 32) {
#pragma unroll
    for (int r2 = 0; r2 < 2; ++r2) {  // A: 128 rows x 32 cols
      int c = r2 * 256 + t;
      int row = c >> 2, s4 = c & 3;
      int slot = s4 ^ (row & 3);
      g2lds16(Ag + row * 2048 + kk + slot * 8, As + c * 8);
    }
#pragma unroll
    for (int r3 = 0; r3 < 3; ++r3) {  // B: 192 rows x 32 cols
      int c = r3 * 256 + t;
      int row = c >> 2, s4 = c & 3;
      int slot = s4 ^ (row & 3);
      g2lds16(Bg + row * 2048 + kk + slot * 8, Bs + c * 8);
    }
    __syncthreads();
    bf16x8 af[4], bfr[6];
#pragma unroll
    for (int mf = 0; mf < 4; ++mf) {
      int row = wr * 64 + mf * 16 + lo;
      af[mf] = ld_bf8(As + row * 32 + ((hi ^ (row & 3)) << 3));
    }
#pragma unroll
    for (int nf = 0; nf < 6; ++nf) {
      int row = wc * 96 + nf * 16 + lo;
      bfr[nf] = ld_bf8(Bs + row * 32 + ((hi ^ (row & 3)) << 3));
    }
    __builtin_amdgcn_s_setprio(1);
#pragma unroll
    for (int mf = 0; mf < 4; ++mf)
#pragma unroll
      for (int nf = 0; nf < 6; ++nf)
        acc[mf][nf] = __builtin_amdgcn_mfma_f32_16x16x32_bf16(
            af[mf], bfr[nf], acc[mf][nf], 0, 0, 0);
    __builtin_amdgcn_s_setprio(0);
    __syncthreads();
  }

  // ---- epilogue: bias + de-interleave via LDS repack, coalesced stores ----
  float bv[6];
  int ch[6];
#pragma unroll
  for (int nf = 0; nf < 6; ++nf) {
    int nl = wc * 96 + nf * 16 + lo;
    bv[nf] = bias[bn + nl];
    ch[nf] = nl % 3;
  }
  const int b_ = bm >> 11;
  const int bh = (b_ << 5) + nt;  // head index == nt
  const float QS = 0.125f * 1.44269504f;

#pragma unroll
  for (int h = 0; h < 2; ++h) {
    if (wr == h) {
#pragma unroll
      for (int mf = 0; mf < 4; ++mf)
#pragma unroll
        for (int nf = 0; nf < 6; ++nf) {
          int rloc = mf * 16 + hi * 4;
          int nl = wc * 96 + nf * 16 + lo;
          f32x4 a = acc[mf][nf];
#pragma unroll
          for (int j = 0; j < 4; ++j) {
            float v = a[j] + bv[nf];
            if (ch[nf] == 0) v *= QS;
            Cs[(rloc + j) * 200 + nl] = f2bf(v);
          }
        }
    }
    __syncthreads();
    const int sbase = (bm & 2047) + h * 64;
    // Q (ch0: nl = 3*hd) and K (ch2: nl = 3*hd+2): row-contiguous 16B stores
#pragma unroll
    for (int it = 0; it < 2; ++it) {
      int slot = it * 256 + t;
      int r = slot >> 3, g = slot & 7;
      ushort8 vq, vk;
#pragma unroll
      for (int u = 0; u < 8; ++u) {
        int hd = g * 8 + u;
        vq[u] = Cs[r * 200 + hd * 3];
        vk[u] = Cs[r * 200 + hd * 3 + 2];
      }
      size_t rowoff = ((size_t)bh * 2048 + sbase + r) * 64 + g * 8;
      *reinterpret_cast<ushort8*>(Qb + rowoff) = vq;
      *reinterpret_cast<ushort8*>(Kb + rowoff) = vk;
    }
    // V (ch1: nl = 3*hd+1) -> VT[bh][hd][s]: 16B runs along s
#pragma unroll
    for (int it = 0; it < 2; ++it) {
      int slot = it * 256 + t;
      int hd = slot >> 3, sg = slot & 7;
      ushort8 vv;
#pragma unroll
      for (int u = 0; u < 8; ++u) vv[u] = Cs[(sg * 8 + u) * 200 + hd * 3 + 1];
      *reinterpret_cast<ushort8*>(VT + ((size_t)bh * 64 + hd) * 2048 + sbase +
                                  sg * 8) = vv;
    }
    __syncthreads();
  }
}

// ---------------- Pass 2: causal flash attention, 1 wave / q-tile -----------
// grid = 4096 one-wave blocks. Mapping bh=bid&63, qt=63-(bid>>6): each CU
// gets ONE bh (K/V locality) and 16 qt values uniformly spanning 0..63 ->
// per-CU work balanced (~520 chunk-units everywhere). K AND V both
// prefetched one chunk ahead. Math is the R3/R5/R6-verified sequence.
__global__ __launch_bounds__(64) void attn(
    const ushort_t* __restrict__ Qb, const ushort_t* __restrict__ Kb,
    const ushort_t* __restrict__ VT, float* __restrict__ out) {
  __shared__ float Ld[32 * 66];  // 8448 B, wave-private
  const int l = threadIdx.x;
  const int ql = l & 31, hi = l >> 5;

  const int bid = blockIdx.x;
  const int bh = bid & 63;        // consecutive bids -> different CUs, one bh/CU
  const int qt = 63 - (bid >> 6); // uniform depth coverage per CU
  const int q0 = qt * 32;
  const int nch = qt + 1;

  const ushort_t* qp = Qb + (bh * 2048 + q0 + ql) * 64 + hi * 8;
  bf16x8 qf[4];
#pragma unroll
  for (int dc = 0; dc < 4; ++dc) qf[dc] = ld_bf8(qp + dc * 16);

  f32x16 o0, o1;
#pragma unroll
  for (int r = 0; r < 16; ++r) { o0[r] = 0.f; o1[r] = 0.f; }
  float mr = -1e30f, lr = 0.f;

  const ushort_t* kbase = Kb + bh * 2048 * 64 + hi * 8;
  const ushort_t* vbase = VT + (bh * 64 + ql) * 2048 + hi * 8;

  // preload chunk 0: K and V fragments
  bf16x8 kf[4], vf0[2], vf1[2];
  {
    const ushort_t* kp = kbase + ql * 64;
#pragma unroll
    for (int dc = 0; dc < 4; ++dc) kf[dc] = ld_bf8(kp + dc * 16);
#pragma unroll
    for (int s = 0; s < 2; ++s) {
      const ushort_t* vp = vbase + s * 16;
      vf0[s] = ld_bf8(vp);
      vf1[s] = ld_bf8(vp + 32 * 2048);
    }
  }

  for (int c = 0; c < nch; ++c) {
    const int cn = (c + 1 < nch) ? (c + 1) : c;
    // prefetch next chunk's K and V (clamped on last iter)
    const ushort_t* kpn = kbase + (cn * 32 + ql) * 64;
    bf16x8 kn[4], vn0[2], vn1[2];
#pragma unroll
    for (int dc = 0; dc < 4; ++dc) kn[dc] = ld_bf8(kpn + dc * 16);
#pragma unroll
    for (int s = 0; s < 2; ++s) {
      const ushort_t* vpn = vbase + cn * 32 + s * 16;
      vn0[s] = ld_bf8(vpn);
      vn1[s] = ld_bf8(vpn + 32 * 2048);
    }

    f32x16 p;
#pragma unroll
    for (int r = 0; r < 16; ++r) p[r] = 0.f;
    __builtin_amdgcn_s_setprio(1);
#pragma unroll
    for (int dc = 0; dc < 4; ++dc)
      p = __builtin_amdgcn_mfma_f32_32x32x16_bf16(kf[dc], qf[dc], p, 0, 0, 0);
    __builtin_amdgcn_s_setprio(0);
    if (c == nch - 1) {  // diagonal chunk: mask kv > q
#pragma unroll
      for (int r = 0; r < 16; ++r) {
        int kvr = (r & 3) + 8 * (r >> 2) + 4 * hi;
        if (kvr > ql) p[r] = -1e30f;
      }
    }
    float mx = p[0];
#pragma unroll
    for (int r = 1; r < 16; ++r) mx = fmaxf(mx, p[r]);
    mx = fmaxf(mx, __shfl_xor(mx, 32));
    float mn = fmaxf(mr, mx);
    float scl = ex2(mr - mn);
    mr = mn;
    float sum = 0.f;
#pragma unroll
    for (int r = 0; r < 16; ++r) {
      p[r] = ex2(p[r] - mn);
      sum += p[r];
    }
    sum += __shfl_xor(sum, 32);
    lr = lr * scl + sum;
#pragma unroll
    for (int r = 0; r < 16; ++r) { o0[r] *= scl; o1[r] *= scl; }

    // P^T -> bf16 B-fragments, in-register (cvt_pk + lane^32 exchange)
    __builtin_amdgcn_s_setprio(1);
#pragma unroll
    for (int s = 0; s < 2; ++s) {
      int x0 = cvtpk(p[8 * s + 0], p[8 * s + 1]);
      int x1 = cvtpk(p[8 * s + 2], p[8 * s + 3]);
      int y0 = cvtpk(p[8 * s + 4], p[8 * s + 5]);
      int y1 = cvtpk(p[8 * s + 6], p[8 * s + 7]);
      int ox0 = __shfl_xor(x0, 32);
      int ox1 = __shfl_xor(x1, 32);
      int oy0 = __shfl_xor(y0, 32);
      int oy1 = __shfl_xor(y1, 32);
      int4v wv;
      wv[0] = hi ? oy0 : x0;
      wv[1] = hi ? oy1 : x1;
      wv[2] = hi ? y0 : ox0;
      wv[3] = hi ? y1 : ox1;
      bf16x8 pf = __builtin_bit_cast(bf16x8, wv);
      o0 = __builtin_amdgcn_mfma_f32_32x32x16_bf16(vf0[s], pf, o0, 0, 0, 0);
      o1 = __builtin_amdgcn_mfma_f32_32x32x16_bf16(vf1[s], pf, o1, 0, 0, 0);
    }
    __builtin_amdgcn_s_setprio(0);
#pragma unroll
    for (int dc = 0; dc < 4; ++dc) kf[dc] = kn[dc];
#pragma unroll
    for (int s = 0; s < 2; ++s) {
      vf0[s] = vn0[s];
      vf1[s] = vn1[s];
    }
  }

  // epilogue: normalize, wave-private LDS detranspose, coalesced row stores
  const float inv = 1.0f / lr;
#pragma unroll
  for (int r = 0; r < 16; ++r) {
    int hdv = (r & 3) + 8 * (r >> 2) + 4 * hi;
    Ld[ql * 66 + hdv] = o0[r] * inv;
    Ld[ql * 66 + 32 + hdv] = o1[r] * inv;
  }
  __syncthreads();
  const int b_ = bh >> 5, h = bh & 31;
  float* op = out + (size_t)(b_ * 2048 + q0) * 2048 + h * 64 + l;
#pragma unroll
  for (int i = 0; i < 32; ++i) {
    op[(size_t)i * 2048] = Ld[i * 66 + l];
  }
}

// ---------------------------------------------------------------------------
extern "C" void kernel_launch(void* const* d_in, const int* in_sizes, int n_in,
                              void* d_out, int out_size, void* d_ws,
                              size_t ws_size, hipStream_t stream) {
  (void)in_sizes; (void)n_in; (void)out_size; (void)ws_size;
  const float* hs = (const float*)d_in[0];    // [2,2048,2048]
  const float* W = (const float*)d_in[1];     // [2048,6144]
  const float* bias = (const float*)d_in[2];  // [6144]
  float* out = (float*)d_out;

  char* ws = (char*)d_ws;
  ushort_t* Abf = (ushort_t*)(ws);                        // 16 MiB  [4096][2048]
  ushort_t* Wt = (ushort_t*)(ws + (16u << 20));           // 24 MiB  [6144][2048]
  ushort_t* Qb = (ushort_t*)(ws + (40u << 20));           // 16 MiB  [64][2048][64]
  ushort_t* Kb = (ushort_t*)(ws + (56u << 20));           // 16 MiB  [64][2048][64]
  ushort_t* VT = (ushort_t*)(ws + (72u << 20));           // 16 MiB  [64][64][2048]

  hipLaunchKernelGGL(cvt_hs, dim3(4096), dim3(256), 0, stream, hs, Abf);
  hipLaunchKernelGGL(transpose_W, dim3(3072), dim3(256), 0, stream, W, Wt);
  hipLaunchKernelGGL(gemm_qkv, dim3(1024), dim3(256), 0, stream, Abf, Wt, bias,
                     Qb, Kb, VT);
  hipLaunchKernelGGL(attn, dim3(4096), dim3(64), 0, stream, Qb, Kb, VT, out);
}

// Round 8
// 271.291 us; speedup vs baseline: 2.2359x; 1.0023x over previous
//
#include <hip/hip_runtime.h>
#include <hip/hip_bf16.h>
#include <stdint.h>

// Problem constants: B=2, S=2048, D=2048, H=32, HD=64, 3D=6144, M=B*S=4096, K=2048
typedef unsigned short ushort_t;
typedef __bf16 bf16x8 __attribute__((ext_vector_type(8)));
typedef float f32x4 __attribute__((ext_vector_type(4)));
typedef float f32x16 __attribute__((ext_vector_type(16)));
typedef int int4v __attribute__((ext_vector_type(4)));
typedef ushort_t ushort8 __attribute__((ext_vector_type(8)));

__device__ __forceinline__ ushort_t f2bf(float f) {
  union { float f; unsigned int u; } v; v.f = f;
  unsigned int r = v.u + 0x7fffu + ((v.u >> 16) & 1u);  // RNE
  return (ushort_t)(r >> 16);
}

__device__ __forceinline__ bf16x8 ld_bf8(const ushort_t* p) {
  return *reinterpret_cast<const bf16x8*>(p);
}

__device__ __forceinline__ void g2lds16(const void* g, void* l) {
  __builtin_amdgcn_global_load_lds(
      (const __attribute__((address_space(1))) unsigned int*)g,
      (__attribute__((address_space(3))) unsigned int*)l,
      16, 0, 0);
}

__device__ __forceinline__ float ex2(float x) { return __builtin_amdgcn_exp2f(x); }

// v_cvt_pk_bf16_f32: word = {lo: bf16(a), hi: bf16(b)}
__device__ __forceinline__ int cvtpk(float a, float b) {
  int r;
  asm("v_cvt_pk_bf16_f32 %0, %1, %2" : "=v"(r) : "v"(a), "v"(b));
  return r;
}

// ---------------- Pass 0a: hidden_states f32 -> bf16 (same layout) ----------
__global__ __launch_bounds__(256) void cvt_hs(const float* __restrict__ in,
                                              ushort_t* __restrict__ out) {
  int i = (blockIdx.x * 256 + threadIdx.x) * 8;
  float4 a = *reinterpret_cast<const float4*>(in + i);
  float4 b = *reinterpret_cast<const float4*>(in + i + 4);
  ushort8 r;
  r[0] = f2bf(a.x); r[1] = f2bf(a.y); r[2] = f2bf(a.z); r[3] = f2bf(a.w);
  r[4] = f2bf(b.x); r[5] = f2bf(b.y); r[6] = f2bf(b.z); r[7] = f2bf(b.w);
  *reinterpret_cast<ushort8*>(out + i) = r;
}

// ---------------- Pass 0b: W [2048][6144] f32 -> Wt [6144][2048] bf16 -------
__global__ __launch_bounds__(256) void transpose_W(const float* __restrict__ Win,
                                                   ushort_t* __restrict__ Wt) {
  __shared__ ushort_t T[64][65];
  const int t = threadIdx.x;
  const int k0 = (blockIdx.x & 31) * 64;
  const int n0 = (blockIdx.x >> 5) * 64;
#pragma unroll
  for (int i = 0; i < 16; ++i) {
    int idx = i * 256 + t;
    int r = idx >> 6, c = idx & 63;
    T[r][c] = f2bf(Win[(k0 + r) * 6144 + n0 + c]);
  }
  __syncthreads();
#pragma unroll
  for (int i = 0; i < 16; ++i) {
    int idx = i * 256 + t;
    int nr = idx >> 6, kc = idx & 63;
    Wt[(n0 + nr) * 2048 + k0 + kc] = T[kc][nr];
  }
}

// ---------------- Pass 1: QKV GEMM, head-aligned BN=192 ---------------------
// Tile 128m x 192n (= one head's q,v,k interleaved columns). Waves 2x2, each
// 64m x 96n (4x6 frags). LDS slot swizzle f(row)=(row&3)^((row>>2)&3): each
// f-value appears 2x per 16-row read group -> 2-way bank aliasing (free).
// Q pre-scaled by 0.125*log2(e) so attention can use exp2 directly.
__global__ __launch_bounds__(256, 2) void gemm_qkv(
    const ushort_t* __restrict__ A, const ushort_t* __restrict__ Bt,
    const float* __restrict__ bias,
    ushort_t* __restrict__ Qb, ushort_t* __restrict__ Kb,
    ushort_t* __restrict__ VT) {
  __shared__ __align__(16) char smem[25600];
  ushort_t* As = (ushort_t*)smem;            // [128][32]
  ushort_t* Bs = (ushort_t*)(smem + 8192);   // [192][32]
  ushort_t* Cs = (ushort_t*)smem;            // [64][200] epilogue alias
  const int t = threadIdx.x;
  const int w = t >> 6, l = t & 63;
  const int lo = l & 15, hi = l >> 4;
  const int wr = w >> 1, wc = w & 1;

  int bid = blockIdx.x;
  int swz = (bid & 7) * 128 + (bid >> 3);  // bijective (1024 = 8*128)
  const int mt = swz & 31, nt = swz >> 5;  // 32 x 32 tiles
  const int bm = mt * 128;
  const int bn = nt * 192;

  f32x4 acc[4][6];
#pragma unroll
  for (int i = 0; i < 4; ++i)
#pragma unroll
    for (int j = 0; j < 6; ++j) acc[i][j] = f32x4{0.f, 0.f, 0.f, 0.f};

  const ushort_t* Ag = A + (size_t)bm * 2048;
  const ushort_t* Bg = Bt + (size_t)bn * 2048;

  for (int kk = 0; kk < 2048; kk += 32) {
#pragma unroll
    for (int r2 = 0; r2 < 2; ++r2) {  // A: 128 rows x 32 cols
      int c = r2 * 256 + t;
      int row = c >> 2, s4 = c & 3;
      int slot = s4 ^ ((row & 3) ^ ((row >> 2) & 3));
      g2lds16(Ag + row * 2048 + kk + slot * 8, As + c * 8);
    }
#pragma unroll
    for (int r3 = 0; r3 < 3; ++r3) {  // B: 192 rows x 32 cols
      int c = r3 * 256 + t;
      int row = c >> 2, s4 = c & 3;
      int slot = s4 ^ ((row & 3) ^ ((row >> 2) & 3));
      g2lds16(Bg + row * 2048 + kk + slot * 8, Bs + c * 8);
    }
    __syncthreads();
    bf16x8 af[4], bfr[6];
#pragma unroll
    for (int mf = 0; mf < 4; ++mf) {
      int row = wr * 64 + mf * 16 + lo;
      int fr = (row & 3) ^ ((row >> 2) & 3);
      af[mf] = ld_bf8(As + row * 32 + ((hi ^ fr) << 3));
    }
#pragma unroll
    for (int nf = 0; nf < 6; ++nf) {
      int row = wc * 96 + nf * 16 + lo;
      int fr = (row & 3) ^ ((row >> 2) & 3);
      bfr[nf] = ld_bf8(Bs + row * 32 + ((hi ^ fr) << 3));
    }
    __builtin_amdgcn_s_setprio(1);
#pragma unroll
    for (int mf = 0; mf < 4; ++mf)
#pragma unroll
      for (int nf = 0; nf < 6; ++nf)
        acc[mf][nf] = __builtin_amdgcn_mfma_f32_16x16x32_bf16(
            af[mf], bfr[nf], acc[mf][nf], 0, 0, 0);
    __builtin_amdgcn_s_setprio(0);
    __syncthreads();
  }

  // ---- epilogue: bias + de-interleave via LDS repack, coalesced stores ----
  float bv[6];
  int ch[6];
#pragma unroll
  for (int nf = 0; nf < 6; ++nf) {
    int nl = wc * 96 + nf * 16 + lo;
    bv[nf] = bias[bn + nl];
    ch[nf] = nl % 3;
  }
  const int b_ = bm >> 11;
  const int bh = (b_ << 5) + nt;  // head index == nt
  const float QS = 0.125f * 1.44269504f;

#pragma unroll
  for (int h = 0; h < 2; ++h) {
    if (wr == h) {
#pragma unroll
      for (int mf = 0; mf < 4; ++mf)
#pragma unroll
        for (int nf = 0; nf < 6; ++nf) {
          int rloc = mf * 16 + hi * 4;
          int nl = wc * 96 + nf * 16 + lo;
          f32x4 a = acc[mf][nf];
#pragma unroll
          for (int j = 0; j < 4; ++j) {
            float v = a[j] + bv[nf];
            if (ch[nf] == 0) v *= QS;
            Cs[(rloc + j) * 200 + nl] = f2bf(v);
          }
        }
    }
    __syncthreads();
    const int sbase = (bm & 2047) + h * 64;
    // Q (ch0: nl = 3*hd) and K (ch2: nl = 3*hd+2): row-contiguous 16B stores
#pragma unroll
    for (int it = 0; it < 2; ++it) {
      int slot = it * 256 + t;
      int r = slot >> 3, g = slot & 7;
      ushort8 vq, vk;
#pragma unroll
      for (int u = 0; u < 8; ++u) {
        int hd = g * 8 + u;
        vq[u] = Cs[r * 200 + hd * 3];
        vk[u] = Cs[r * 200 + hd * 3 + 2];
      }
      size_t rowoff = ((size_t)bh * 2048 + sbase + r) * 64 + g * 8;
      *reinterpret_cast<ushort8*>(Qb + rowoff) = vq;
      *reinterpret_cast<ushort8*>(Kb + rowoff) = vk;
    }
    // V (ch1: nl = 3*hd+1) -> VT[bh][hd][s]: 16B runs along s
#pragma unroll
    for (int it = 0; it < 2; ++it) {
      int slot = it * 256 + t;
      int hd = slot >> 3, sg = slot & 7;
      ushort8 vv;
#pragma unroll
      for (int u = 0; u < 8; ++u) vv[u] = Cs[(sg * 8 + u) * 200 + hd * 3 + 1];
      *reinterpret_cast<ushort8*>(VT + ((size_t)bh * 64 + hd) * 2048 + sbase +
                                  sg * 8) = vv;
    }
    __syncthreads();
  }
}

// ---------------- Pass 2: causal flash attention, 1 wave / q-tile -----------
// grid = 4096 one-wave blocks. Mapping bh=bid&63, qt=63-(bid>>6): per-CU work
// balanced, one bh per CU. K AND V prefetched one chunk ahead. Defer-max
// (T13): rescale O only when the chunk max grows >10 (log2 domain); otherwise
// identical math with scl==1 skipped. Core sequence otherwise R3-verified.
__global__ __launch_bounds__(64) void attn(
    const ushort_t* __restrict__ Qb, const ushort_t* __restrict__ Kb,
    const ushort_t* __restrict__ VT, float* __restrict__ out) {
  __shared__ float Ld[32 * 66];  // 8448 B, wave-private
  const int l = threadIdx.x;
  const int ql = l & 31, hi = l >> 5;

  const int bid = blockIdx.x;
  const int bh = bid & 63;        // consecutive bids -> different CUs, one bh/CU
  const int qt = 63 - (bid >> 6); // uniform depth coverage per CU
  const int q0 = qt * 32;
  const int nch = qt + 1;

  const ushort_t* qp = Qb + (bh * 2048 + q0 + ql) * 64 + hi * 8;
  bf16x8 qf[4];
#pragma unroll
  for (int dc = 0; dc < 4; ++dc) qf[dc] = ld_bf8(qp + dc * 16);

  f32x16 o0, o1;
#pragma unroll
  for (int r = 0; r < 16; ++r) { o0[r] = 0.f; o1[r] = 0.f; }
  float mr = -1e30f, lr = 0.f;

  const ushort_t* kbase = Kb + bh * 2048 * 64 + hi * 8;
  const ushort_t* vbase = VT + (bh * 64 + ql) * 2048 + hi * 8;

  // preload chunk 0: K and V fragments
  bf16x8 kf[4], vf0[2], vf1[2];
  {
    const ushort_t* kp = kbase + ql * 64;
#pragma unroll
    for (int dc = 0; dc < 4; ++dc) kf[dc] = ld_bf8(kp + dc * 16);
#pragma unroll
    for (int s = 0; s < 2; ++s) {
      const ushort_t* vp = vbase + s * 16;
      vf0[s] = ld_bf8(vp);
      vf1[s] = ld_bf8(vp + 32 * 2048);
    }
  }

  for (int c = 0; c < nch; ++c) {
    const int cn = (c + 1 < nch) ? (c + 1) : c;
    // prefetch next chunk's K and V (clamped on last iter)
    const ushort_t* kpn = kbase + (cn * 32 + ql) * 64;
    bf16x8 kn[4], vn0[2], vn1[2];
#pragma unroll
    for (int dc = 0; dc < 4; ++dc) kn[dc] = ld_bf8(kpn + dc * 16);
#pragma unroll
    for (int s = 0; s < 2; ++s) {
      const ushort_t* vpn = vbase + cn * 32 + s * 16;
      vn0[s] = ld_bf8(vpn);
      vn1[s] = ld_bf8(vpn + 32 * 2048);
    }

    f32x16 p;
#pragma unroll
    for (int r = 0; r < 16; ++r) p[r] = 0.f;
    __builtin_amdgcn_s_setprio(1);
#pragma unroll
    for (int dc = 0; dc < 4; ++dc)
      p = __builtin_amdgcn_mfma_f32_32x32x16_bf16(kf[dc], qf[dc], p, 0, 0, 0);
    __builtin_amdgcn_s_setprio(0);
    if (c == nch - 1) {  // diagonal chunk: mask kv > q
#pragma unroll
      for (int r = 0; r < 16; ++r) {
        int kvr = (r & 3) + 8 * (r >> 2) + 4 * hi;
        if (kvr > ql) p[r] = -1e30f;
      }
    }
    float mx = p[0];
#pragma unroll
    for (int r = 1; r < 16; ++r) mx = fmaxf(mx, p[r]);
    mx = fmaxf(mx, __shfl_xor(mx, 32));
    // defer-max: rescale only on material max growth (log2 domain, thr=10)
    if (__any(mx > mr + 10.0f)) {
      float mn = fmaxf(mr, mx);
      float scl = ex2(mr - mn);
      mr = mn;
      lr *= scl;
#pragma unroll
      for (int r = 0; r < 16; ++r) { o0[r] *= scl; o1[r] *= scl; }
    }
    float sum = 0.f;
#pragma unroll
    for (int r = 0; r < 16; ++r) {
      p[r] = ex2(p[r] - mr);
      sum += p[r];
    }
    sum += __shfl_xor(sum, 32);
    lr += sum;

    // P^T -> bf16 B-fragments, in-register (cvt_pk + lane^32 exchange)
    __builtin_amdgcn_s_setprio(1);
#pragma unroll
    for (int s = 0; s < 2; ++s) {
      int x0 = cvtpk(p[8 * s + 0], p[8 * s + 1]);
      int x1 = cvtpk(p[8 * s + 2], p[8 * s + 3]);
      int y0 = cvtpk(p[8 * s + 4], p[8 * s + 5]);
      int y1 = cvtpk(p[8 * s + 6], p[8 * s + 7]);
      int ox0 = __shfl_xor(x0, 32);
      int ox1 = __shfl_xor(x1, 32);
      int oy0 = __shfl_xor(y0, 32);
      int oy1 = __shfl_xor(y1, 32);
      int4v wv;
      wv[0] = hi ? oy0 : x0;
      wv[1] = hi ? oy1 : x1;
      wv[2] = hi ? y0 : ox0;
      wv[3] = hi ? y1 : ox1;
      bf16x8 pf = __builtin_bit_cast(bf16x8, wv);
      o0 = __builtin_amdgcn_mfma_f32_32x32x16_bf16(vf0[s], pf, o0, 0, 0, 0);
      o1 = __builtin_amdgcn_mfma_f32_32x32x16_bf16(vf1[s], pf, o1, 0, 0, 0);
    }
    __builtin_amdgcn_s_setprio(0);
#pragma unroll
    for (int dc = 0; dc < 4; ++dc) kf[dc] = kn[dc];
#pragma unroll
    for (int s = 0; s < 2; ++s) {
      vf0[s] = vn0[s];
      vf1[s] = vn1[s];
    }
  }

  // epilogue: normalize, wave-private LDS detranspose, coalesced row stores
  const float inv = 1.0f / lr;
#pragma unroll
  for (int r = 0; r < 16; ++r) {
    int hdv = (r & 3) + 8 * (r >> 2) + 4 * hi;
    Ld[ql * 66 + hdv] = o0[r] * inv;
    Ld[ql * 66 + 32 + hdv] = o1[r] * inv;
  }
  __syncthreads();
  const int b_ = bh >> 5, h = bh & 31;
  float* op = out + (size_t)(b_ * 2048 + q0) * 2048 + h * 64 + l;
#pragma unroll
  for (int i = 0; i < 32; ++i) {
    op[(size_t)i * 2048] = Ld[i * 66 + l];
  }
}

// ---------------------------------------------------------------------------
extern "C" void kernel_launch(void* const* d_in, const int* in_sizes, int n_in,
                              void* d_out, int out_size, void* d_ws,
                              size_t ws_size, hipStream_t stream) {
  (void)in_sizes; (void)n_in; (void)out_size; (void)ws_size;
  const float* hs = (const float*)d_in[0];    // [2,2048,2048]
  const float* W = (const float*)d_in[1];     // [2048,6144]
  const float* bias = (const float*)d_in[2];  // [6144]
  float* out = (float*)d_out;

  char* ws = (char*)d_ws;
  ushort_t* Abf = (ushort_t*)(ws);                        // 16 MiB  [4096][2048]
  ushort_t* Wt = (ushort_t*)(ws + (16u << 20));           // 24 MiB  [6144][2048]
  ushort_t* Qb = (ushort_t*)(ws + (40u << 20));           // 16 MiB  [64][2048][64]
  ushort_t* Kb = (ushort_t*)(ws + (56u << 20));           // 16 MiB  [64][2048][64]
  ushort_t* VT = (ushort_t*)(ws + (72u << 20));           // 16 MiB  [64][64][2048]

  hipLaunchKernelGGL(cvt_hs, dim3(4096), dim3(256), 0, stream, hs, Abf);
  hipLaunchKernelGGL(transpose_W, dim3(3072), dim3(256), 0, stream, W, Wt);
  hipLaunchKernelGGL(gemm_qkv, dim3(1024), dim3(256), 0, stream, Abf, Wt, bias,
                     Qb, Kb, VT);
  hipLaunchKernelGGL(attn, dim3(4096), dim3(64), 0, stream, Qb, Kb, VT, out);
}

// Round 9
// 269.691 us; speedup vs baseline: 2.2491x; 1.0059x over previous
//
#include <hip/hip_runtime.h>
#include <hip/hip_bf16.h>
#include <stdint.h>

// Problem constants: B=2, S=2048, D=2048, H=32, HD=64, 3D=6144, M=B*S=4096, K=2048
typedef unsigned short ushort_t;
typedef __bf16 bf16x8 __attribute__((ext_vector_type(8)));
typedef float f32x4 __attribute__((ext_vector_type(4)));
typedef float f32x16 __attribute__((ext_vector_type(16)));
typedef int int4v __attribute__((ext_vector_type(4)));
typedef ushort_t ushort8 __attribute__((ext_vector_type(8)));

__device__ __forceinline__ ushort_t f2bf(float f) {
  union { float f; unsigned int u; } v; v.f = f;
  unsigned int r = v.u + 0x7fffu + ((v.u >> 16) & 1u);  // RNE
  return (ushort_t)(r >> 16);
}

__device__ __forceinline__ bf16x8 ld_bf8(const ushort_t* p) {
  return *reinterpret_cast<const bf16x8*>(p);
}

__device__ __forceinline__ void g2lds16(const void* g, void* l) {
  __builtin_amdgcn_global_load_lds(
      (const __attribute__((address_space(1))) unsigned int*)g,
      (__attribute__((address_space(3))) unsigned int*)l,
      16, 0, 0);
}

__device__ __forceinline__ float ex2(float x) { return __builtin_amdgcn_exp2f(x); }

// v_cvt_pk_bf16_f32: word = {lo: bf16(a), hi: bf16(b)}
__device__ __forceinline__ int cvtpk(float a, float b) {
  int r;
  asm("v_cvt_pk_bf16_f32 %0, %1, %2" : "=v"(r) : "v"(a), "v"(b));
  return r;
}

// ---------------- Pass 0a: hidden_states f32 -> bf16 (same layout) ----------
__global__ __launch_bounds__(256) void cvt_hs(const float* __restrict__ in,
                                              ushort_t* __restrict__ out) {
  int i = (blockIdx.x * 256 + threadIdx.x) * 8;
  float4 a = *reinterpret_cast<const float4*>(in + i);
  float4 b = *reinterpret_cast<const float4*>(in + i + 4);
  ushort8 r;
  r[0] = f2bf(a.x); r[1] = f2bf(a.y); r[2] = f2bf(a.z); r[3] = f2bf(a.w);
  r[4] = f2bf(b.x); r[5] = f2bf(b.y); r[6] = f2bf(b.z); r[7] = f2bf(b.w);
  *reinterpret_cast<ushort8*>(out + i) = r;
}

// ---------------- Pass 0b: W [2048][6144] f32 -> Wt [6144][2048] bf16 -------
__global__ __launch_bounds__(256) void transpose_W(const float* __restrict__ Win,
                                                   ushort_t* __restrict__ Wt) {
  __shared__ ushort_t T[64][65];
  const int t = threadIdx.x;
  const int k0 = (blockIdx.x & 31) * 64;
  const int n0 = (blockIdx.x >> 5) * 64;
#pragma unroll
  for (int i = 0; i < 16; ++i) {
    int idx = i * 256 + t;
    int r = idx >> 6, c = idx & 63;
    T[r][c] = f2bf(Win[(k0 + r) * 6144 + n0 + c]);
  }
  __syncthreads();
#pragma unroll
  for (int i = 0; i < 16; ++i) {
    int idx = i * 256 + t;
    int nr = idx >> 6, kc = idx & 63;
    Wt[(n0 + nr) * 2048 + k0 + kc] = T[kc][nr];
  }
}

// ---------------- Pass 1: QKV GEMM, head-aligned BN=192, T3-min pipeline ----
// Tile 128m x 192n. Double-buffered LDS; STAGE(t+1) issued BEFORE the
// ds_read+MFMA of tile t; ONE barrier per K-step (drains vmcnt for the next
// buffer and fences readers of the current one). Math identical to R7/R8.
__global__ __launch_bounds__(256, 2) void gemm_qkv(
    const ushort_t* __restrict__ A, const ushort_t* __restrict__ Bt,
    const float* __restrict__ bias,
    ushort_t* __restrict__ Qb, ushort_t* __restrict__ Kb,
    ushort_t* __restrict__ VT) {
  __shared__ __align__(16) char smem[40960];
  ushort_t* A0 = (ushort_t*)smem;             // [128][32] buf0
  ushort_t* A1 = (ushort_t*)(smem + 8192);    // buf1
  ushort_t* B0 = (ushort_t*)(smem + 16384);   // [192][32] buf0
  ushort_t* B1 = (ushort_t*)(smem + 28672);   // buf1
  ushort_t* Cs = (ushort_t*)smem;             // [64][200] epilogue alias
  const int t = threadIdx.x;
  const int w = t >> 6, l = t & 63;
  const int lo = l & 15, hi = l >> 4;
  const int wr = w >> 1, wc = w & 1;

  int bid = blockIdx.x;
  int swz = (bid & 7) * 128 + (bid >> 3);  // bijective (1024 = 8*128)
  const int mt = swz & 31, nt = swz >> 5;  // 32 x 32 tiles
  const int bm = mt * 128;
  const int bn = nt * 192;

  f32x4 acc[4][6];
#pragma unroll
  for (int i = 0; i < 4; ++i)
#pragma unroll
    for (int j = 0; j < 6; ++j) acc[i][j] = f32x4{0.f, 0.f, 0.f, 0.f};

  const ushort_t* Ag = A + (size_t)bm * 2048;
  const ushort_t* Bg = Bt + (size_t)bn * 2048;

#define STAGE(Ad, Bd, kk_)                                       \
  do {                                                           \
    for (int r2 = 0; r2 < 2; ++r2) {                             \
      int c_ = r2 * 256 + t;                                     \
      int row_ = c_ >> 2, s4_ = c_ & 3;                          \
      int slot_ = s4_ ^ ((row_ & 3) ^ ((row_ >> 2) & 3));        \
      g2lds16(Ag + row_ * 2048 + (kk_) + slot_ * 8, (Ad) + c_ * 8); \
    }                                                            \
    for (int r3 = 0; r3 < 3; ++r3) {                             \
      int c_ = r3 * 256 + t;                                     \
      int row_ = c_ >> 2, s4_ = c_ & 3;                          \
      int slot_ = s4_ ^ ((row_ & 3) ^ ((row_ >> 2) & 3));        \
      g2lds16(Bg + row_ * 2048 + (kk_) + slot_ * 8, (Bd) + c_ * 8); \
    }                                                            \
  } while (0)

  STAGE(A0, B0, 0);
  __syncthreads();
  ushort_t *Ac = A0, *Bc = B0, *An = A1, *Bn = B1;

  for (int kk = 0; kk < 2048; kk += 32) {
    if (kk + 32 < 2048) STAGE(An, Bn, kk + 32);  // issue next-tile loads EARLY
    bf16x8 af[4], bfr[6];
#pragma unroll
    for (int mf = 0; mf < 4; ++mf) {
      int row = wr * 64 + mf * 16 + lo;
      int fr = (row & 3) ^ ((row >> 2) & 3);
      af[mf] = ld_bf8(Ac + row * 32 + ((hi ^ fr) << 3));
    }
#pragma unroll
    for (int nf = 0; nf < 6; ++nf) {
      int row = wc * 96 + nf * 16 + lo;
      int fr = (row & 3) ^ ((row >> 2) & 3);
      bfr[nf] = ld_bf8(Bc + row * 32 + ((hi ^ fr) << 3));
    }
    __builtin_amdgcn_s_setprio(1);
#pragma unroll
    for (int mf = 0; mf < 4; ++mf)
#pragma unroll
      for (int nf = 0; nf < 6; ++nf)
        acc[mf][nf] = __builtin_amdgcn_mfma_f32_16x16x32_bf16(
            af[mf], bfr[nf], acc[mf][nf], 0, 0, 0);
    __builtin_amdgcn_s_setprio(0);
    __syncthreads();  // drains next-buffer vmcnt + fences current-buffer reads
    ushort_t* tmp;
    tmp = Ac; Ac = An; An = tmp;
    tmp = Bc; Bc = Bn; Bn = tmp;
  }
#undef STAGE

  // ---- epilogue: bias + de-interleave via LDS repack, coalesced stores ----
  float bv[6];
  int ch[6];
#pragma unroll
  for (int nf = 0; nf < 6; ++nf) {
    int nl = wc * 96 + nf * 16 + lo;
    bv[nf] = bias[bn + nl];
    ch[nf] = nl % 3;
  }
  const int b_ = bm >> 11;
  const int bh = (b_ << 5) + nt;  // head index == nt
  const float QS = 0.125f * 1.44269504f;

#pragma unroll
  for (int h = 0; h < 2; ++h) {
    if (wr == h) {
#pragma unroll
      for (int mf = 0; mf < 4; ++mf)
#pragma unroll
        for (int nf = 0; nf < 6; ++nf) {
          int rloc = mf * 16 + hi * 4;
          int nl = wc * 96 + nf * 16 + lo;
          f32x4 a = acc[mf][nf];
#pragma unroll
          for (int j = 0; j < 4; ++j) {
            float v = a[j] + bv[nf];
            if (ch[nf] == 0) v *= QS;
            Cs[(rloc + j) * 200 + nl] = f2bf(v);
          }
        }
    }
    __syncthreads();
    const int sbase = (bm & 2047) + h * 64;
    // Q (ch0: nl = 3*hd) and K (ch2: nl = 3*hd+2): row-contiguous 16B stores
#pragma unroll
    for (int it = 0; it < 2; ++it) {
      int slot = it * 256 + t;
      int r = slot >> 3, g = slot & 7;
      ushort8 vq, vk;
#pragma unroll
      for (int u = 0; u < 8; ++u) {
        int hd = g * 8 + u;
        vq[u] = Cs[r * 200 + hd * 3];
        vk[u] = Cs[r * 200 + hd * 3 + 2];
      }
      size_t rowoff = ((size_t)bh * 2048 + sbase + r) * 64 + g * 8;
      *reinterpret_cast<ushort8*>(Qb + rowoff) = vq;
      *reinterpret_cast<ushort8*>(Kb + rowoff) = vk;
    }
    // V (ch1: nl = 3*hd+1) -> VT[bh][hd][s]: 16B runs along s
#pragma unroll
    for (int it = 0; it < 2; ++it) {
      int slot = it * 256 + t;
      int hd = slot >> 3, sg = slot & 7;
      ushort8 vv;
#pragma unroll
      for (int u = 0; u < 8; ++u) vv[u] = Cs[(sg * 8 + u) * 200 + hd * 3 + 1];
      *reinterpret_cast<ushort8*>(VT + ((size_t)bh * 64 + hd) * 2048 + sbase +
                                  sg * 8) = vv;
    }
    __syncthreads();
  }
}

// ---------------- attn helpers ----------------------------------------------
__device__ __forceinline__ void ldk(const ushort_t* kbase, int c, int ql,
                                    bf16x8 k[4]) {
  const ushort_t* kp = kbase + (c * 32 + ql) * 64;
#pragma unroll
  for (int dc = 0; dc < 4; ++dc) k[dc] = ld_bf8(kp + dc * 16);
}

__device__ __forceinline__ void ldv(const ushort_t* vbase, int c, bf16x8 v0[2],
                                    bf16x8 v1[2]) {
  const ushort_t* vp = vbase + c * 32;
#pragma unroll
  for (int s = 0; s < 2; ++s) {
    v0[s] = ld_bf8(vp + s * 16);
    v1[s] = ld_bf8(vp + s * 16 + 32 * 2048);
  }
}

__device__ __forceinline__ f32x16 qk_mfma(const bf16x8 k[4], const bf16x8 q[4]) {
  f32x16 p;
#pragma unroll
  for (int r = 0; r < 16; ++r) p[r] = 0.f;
  __builtin_amdgcn_s_setprio(1);
#pragma unroll
  for (int dc = 0; dc < 4; ++dc)
    p = __builtin_amdgcn_mfma_f32_32x32x16_bf16(k[dc], q[dc], p, 0, 0, 0);
  __builtin_amdgcn_s_setprio(0);
  return p;
}

// softmax + PV for one 32-kv chunk (math identical to R7/R8 verified sequence,
// with pairwise trees for max/sum).
__device__ __forceinline__ void sm_pv(f32x16& p, const bf16x8 v0[2],
                                      const bf16x8 v1[2], f32x16& o0,
                                      f32x16& o1, float& mr, float& lr,
                                      bool diag, int ql, int hi) {
  if (diag) {
#pragma unroll
    for (int r = 0; r < 16; ++r) {
      int kvr = (r & 3) + 8 * (r >> 2) + 4 * hi;
      if (kvr > ql) p[r] = -1e30f;
    }
  }
  // pairwise-tree max (fmax exact -> same result, shorter dep chain)
  float a0 = fmaxf(p[0], p[1]), a1 = fmaxf(p[2], p[3]);
  float a2 = fmaxf(p[4], p[5]), a3 = fmaxf(p[6], p[7]);
  float a4 = fmaxf(p[8], p[9]), a5 = fmaxf(p[10], p[11]);
  float a6 = fmaxf(p[12], p[13]), a7 = fmaxf(p[14], p[15]);
  float b0 = fmaxf(a0, a1), b1 = fmaxf(a2, a3);
  float b2 = fmaxf(a4, a5), b3 = fmaxf(a6, a7);
  float mx = fmaxf(fmaxf(b0, b1), fmaxf(b2, b3));
  mx = fmaxf(mx, __shfl_xor(mx, 32));
  // defer-max: rescale only on material max growth (log2 domain, thr=10)
  if (__any(mx > mr + 10.0f)) {
    float mn = fmaxf(mr, mx);
    float scl = ex2(mr - mn);
    mr = mn;
    lr *= scl;
#pragma unroll
    for (int r = 0; r < 16; ++r) { o0[r] *= scl; o1[r] *= scl; }
  }
#pragma unroll
  for (int r = 0; r < 16; ++r) p[r] = ex2(p[r] - mr);
  float s0 = (p[0] + p[1]) + (p[2] + p[3]);
  float s1 = (p[4] + p[5]) + (p[6] + p[7]);
  float s2 = (p[8] + p[9]) + (p[10] + p[11]);
  float s3 = (p[12] + p[13]) + (p[14] + p[15]);
  float sum = (s0 + s1) + (s2 + s3);
  sum += __shfl_xor(sum, 32);
  lr += sum;

  // P^T -> bf16 B-fragments, in-register (cvt_pk + lane^32 exchange)
  __builtin_amdgcn_s_setprio(1);
#pragma unroll
  for (int s = 0; s < 2; ++s) {
    int x0 = cvtpk(p[8 * s + 0], p[8 * s + 1]);
    int x1 = cvtpk(p[8 * s + 2], p[8 * s + 3]);
    int y0 = cvtpk(p[8 * s + 4], p[8 * s + 5]);
    int y1 = cvtpk(p[8 * s + 6], p[8 * s + 7]);
    int ox0 = __shfl_xor(x0, 32);
    int ox1 = __shfl_xor(x1, 32);
    int oy0 = __shfl_xor(y0, 32);
    int oy1 = __shfl_xor(y1, 32);
    int4v wv;
    wv[0] = hi ? oy0 : x0;
    wv[1] = hi ? oy1 : x1;
    wv[2] = hi ? y0 : ox0;
    wv[3] = hi ? y1 : ox1;
    bf16x8 pf = __builtin_bit_cast(bf16x8, wv);
    o0 = __builtin_amdgcn_mfma_f32_32x32x16_bf16(v0[s], pf, o0, 0, 0, 0);
    o1 = __builtin_amdgcn_mfma_f32_32x32x16_bf16(v1[s], pf, o1, 0, 0, 0);
  }
  __builtin_amdgcn_s_setprio(0);
}

// ---------------- Pass 2: causal flash attention, 1 wave / q-tile -----------
// 2-deep score pipeline (unroll-by-2 ping-pong): each body issues QK MFMAs for
// chunk c+1 FIRST (operands already in regs), then runs softmax+PV of chunk c
// on the VALU while they execute. Per-chunk math identical to R7/R8.
__global__ __launch_bounds__(64) void attn(
    const ushort_t* __restrict__ Qb, const ushort_t* __restrict__ Kb,
    const ushort_t* __restrict__ VT, float* __restrict__ out) {
  __shared__ float Ld[32 * 66];  // 8448 B, wave-private
  const int l = threadIdx.x;
  const int ql = l & 31, hi = l >> 5;

  const int bid = blockIdx.x;
  const int bh = bid & 63;        // one bh per CU (L2 locality)
  const int qt = 63 - (bid >> 6); // uniform depth coverage per CU
  const int q0 = qt * 32;
  const int nch = qt + 1;

  const ushort_t* qp = Qb + (bh * 2048 + q0 + ql) * 64 + hi * 8;
  bf16x8 qf[4];
#pragma unroll
  for (int dc = 0; dc < 4; ++dc) qf[dc] = ld_bf8(qp + dc * 16);

  f32x16 o0, o1;
#pragma unroll
  for (int r = 0; r < 16; ++r) { o0[r] = 0.f; o1[r] = 0.f; }
  float mr = -1e30f, lr = 0.f;

  const ushort_t* kbase = Kb + bh * 2048 * 64 + hi * 8;
  const ushort_t* vbase = VT + (bh * 64 + ql) * 2048 + hi * 8;

  bf16x8 kA[4], kB[4], vA0[2], vA1[2], vB0[2], vB1[2];
  f32x16 pA, pB;

  // prologue: scores for chunk 0; operands for chunk 1
  ldk(kbase, 0, ql, kA);
  ldv(vbase, 0, vA0, vA1);
  pA = qk_mfma(kA, qf);
  {
    const int c1 = (nch > 1) ? 1 : 0;
    ldk(kbase, c1, ql, kB);
    ldv(vbase, c1, vB0, vB1);
  }

  int c = 0;
  for (; c + 2 <= nch; c += 2) {
    // A-body: process chunk c (pA, vA); issue QK for chunk c+1 (kB)
    pB = qk_mfma(kB, qf);
    {
      const int cp = (c + 2 < nch) ? c + 2 : c;
      ldk(kbase, cp, ql, kA);  // prefetch K(c+2)
    }
    sm_pv(pA, vA0, vA1, o0, o1, mr, lr, false, ql, hi);  // c <= nch-2: not diag
    {
      const int cp = (c + 2 < nch) ? c + 2 : c;
      ldv(vbase, cp, vA0, vA1);  // prefetch V(c+2)
    }
    // B-body: process chunk c+1 (pB, vB); issue QK for chunk c+2 (kA)
    if (c + 2 < nch) pA = qk_mfma(kA, qf);
    {
      const int cp = (c + 3 < nch) ? c + 3 : c;
      ldk(kbase, cp, ql, kB);  // prefetch K(c+3)
    }
    sm_pv(pB, vB0, vB1, o0, o1, mr, lr, (c + 1 == nch - 1), ql, hi);
    {
      const int cp = (c + 3 < nch) ? c + 3 : c;
      ldv(vbase, cp, vB0, vB1);  // prefetch V(c+3)
    }
  }
  if (c < nch) {  // odd tail: chunk c == nch-1 (diagonal), scores in pA
    sm_pv(pA, vA0, vA1, o0, o1, mr, lr, true, ql, hi);
  }

  // epilogue: normalize, wave-private LDS detranspose, coalesced row stores
  const float inv = 1.0f / lr;
#pragma unroll
  for (int r = 0; r < 16; ++r) {
    int hdv = (r & 3) + 8 * (r >> 2) + 4 * hi;
    Ld[ql * 66 + hdv] = o0[r] * inv;
    Ld[ql * 66 + 32 + hdv] = o1[r] * inv;
  }
  __syncthreads();
  const int b_ = bh >> 5, h = bh & 31;
  float* op = out + (size_t)(b_ * 2048 + q0) * 2048 + h * 64 + l;
#pragma unroll
  for (int i = 0; i < 32; ++i) {
    op[(size_t)i * 2048] = Ld[i * 66 + l];
  }
}

// ---------------------------------------------------------------------------
extern "C" void kernel_launch(void* const* d_in, const int* in_sizes, int n_in,
                              void* d_out, int out_size, void* d_ws,
                              size_t ws_size, hipStream_t stream) {
  (void)in_sizes; (void)n_in; (void)out_size; (void)ws_size;
  const float* hs = (const float*)d_in[0];    // [2,2048,2048]
  const float* W = (const float*)d_in[1];     // [2048,6144]
  const float* bias = (const float*)d_in[2];  // [6144]
  float* out = (float*)d_out;

  char* ws = (char*)d_ws;
  ushort_t* Abf = (ushort_t*)(ws);                        // 16 MiB  [4096][2048]
  ushort_t* Wt = (ushort_t*)(ws + (16u << 20));           // 24 MiB  [6144][2048]
  ushort_t* Qb = (ushort_t*)(ws + (40u << 20));           // 16 MiB  [64][2048][64]
  ushort_t* Kb = (ushort_t*)(ws + (56u << 20));           // 16 MiB  [64][2048][64]
  ushort_t* VT = (ushort_t*)(ws + (72u << 20));           // 16 MiB  [64][64][2048]

  hipLaunchKernelGGL(cvt_hs, dim3(4096), dim3(256), 0, stream, hs, Abf);
  hipLaunchKernelGGL(transpose_W, dim3(3072), dim3(256), 0, stream, W, Wt);
  hipLaunchKernelGGL(gemm_qkv, dim3(1024), dim3(256), 0, stream, Abf, Wt, bias,
                     Qb, Kb, VT);
  hipLaunchKernelGGL(attn, dim3(4096), dim3(64), 0, stream, Qb, Kb, VT, out);
}

// Round 11
// 263.398 us; speedup vs baseline: 2.3029x; 1.0239x over previous
//
#include <hip/hip_runtime.h>
#include <hip/hip_bf16.h>
#include <stdint.h>

// Problem constants: B=2, S=2048, D=2048, H=32, HD=64, 3D=6144, M=B*S=4096, K=2048
typedef unsigned short ushort_t;
typedef __bf16 bf16x8 __attribute__((ext_vector_type(8)));
typedef float f32x4 __attribute__((ext_vector_type(4)));
typedef float f32x16 __attribute__((ext_vector_type(16)));
typedef int int4v __attribute__((ext_vector_type(4)));
typedef ushort_t ushort8 __attribute__((ext_vector_type(8)));

__device__ __forceinline__ ushort_t f2bf(float f) {
  union { float f; unsigned int u; } v; v.f = f;
  unsigned int r = v.u + 0x7fffu + ((v.u >> 16) & 1u);  // RNE
  return (ushort_t)(r >> 16);
}

__device__ __forceinline__ bf16x8 ld_bf8(const ushort_t* p) {
  return *reinterpret_cast<const bf16x8*>(p);
}

__device__ __forceinline__ void g2lds16(const void* g, void* l) {
  __builtin_amdgcn_global_load_lds(
      (const __attribute__((address_space(1))) unsigned int*)g,
      (__attribute__((address_space(3))) unsigned int*)l,
      16, 0, 0);
}

__device__ __forceinline__ float ex2(float x) { return __builtin_amdgcn_exp2f(x); }

// v_cvt_pk_bf16_f32: word = {lo: bf16(a), hi: bf16(b)}
__device__ __forceinline__ int cvtpk(float a, float b) {
  int r;
  asm("v_cvt_pk_bf16_f32 %0, %1, %2" : "=v"(r) : "v"(a), "v"(b));
  return r;
}

// ---------------- Pass 0a: hidden_states f32 -> bf16 (same layout) ----------
__global__ __launch_bounds__(256) void cvt_hs(const float* __restrict__ in,
                                              ushort_t* __restrict__ out) {
  int i = (blockIdx.x * 256 + threadIdx.x) * 8;
  float4 a = *reinterpret_cast<const float4*>(in + i);
  float4 b = *reinterpret_cast<const float4*>(in + i + 4);
  ushort8 r;
  r[0] = f2bf(a.x); r[1] = f2bf(a.y); r[2] = f2bf(a.z); r[3] = f2bf(a.w);
  r[4] = f2bf(b.x); r[5] = f2bf(b.y); r[6] = f2bf(b.z); r[7] = f2bf(b.w);
  *reinterpret_cast<ushort8*>(out + i) = r;
}

// ---------------- Pass 0b: W [2048][6144] f32 -> Wt [6144][2048] bf16 -------
__global__ __launch_bounds__(256) void transpose_W(const float* __restrict__ Win,
                                                   ushort_t* __restrict__ Wt) {
  __shared__ ushort_t T[64][65];
  const int t = threadIdx.x;
  const int k0 = (blockIdx.x & 31) * 64;
  const int n0 = (blockIdx.x >> 5) * 64;
#pragma unroll
  for (int i = 0; i < 16; ++i) {
    int idx = i * 256 + t;
    int r = idx >> 6, c = idx & 63;
    T[r][c] = f2bf(Win[(k0 + r) * 6144 + n0 + c]);
  }
  __syncthreads();
#pragma unroll
  for (int i = 0; i < 16; ++i) {
    int idx = i * 256 + t;
    int nr = idx >> 6, kc = idx & 63;
    Wt[(n0 + nr) * 2048 + k0 + kc] = T[kc][nr];
  }
}

// ---------------- Pass 1: QKV GEMM, head-aligned BN=192, T3-min pipeline ----
// (R9-verified: double-buffered LDS, STAGE(t+1) before compute, 1 barrier/iter)
__global__ __launch_bounds__(256, 2) void gemm_qkv(
    const ushort_t* __restrict__ A, const ushort_t* __restrict__ Bt,
    const float* __restrict__ bias,
    ushort_t* __restrict__ Qb, ushort_t* __restrict__ Kb,
    ushort_t* __restrict__ VT) {
  __shared__ __align__(16) char smem[40960];
  ushort_t* A0 = (ushort_t*)smem;             // [128][32] buf0
  ushort_t* A1 = (ushort_t*)(smem + 8192);    // buf1
  ushort_t* B0 = (ushort_t*)(smem + 16384);   // [192][32] buf0
  ushort_t* B1 = (ushort_t*)(smem + 28672);   // buf1
  ushort_t* Cs = (ushort_t*)smem;             // [64][200] epilogue alias
  const int t = threadIdx.x;
  const int w = t >> 6, l = t & 63;
  const int lo = l & 15, hi = l >> 4;
  const int wr = w >> 1, wc = w & 1;

  int bid = blockIdx.x;
  int swz = (bid & 7) * 128 + (bid >> 3);  // bijective (1024 = 8*128)
  const int mt = swz & 31, nt = swz >> 5;  // 32 x 32 tiles
  const int bm = mt * 128;
  const int bn = nt * 192;

  f32x4 acc[4][6];
#pragma unroll
  for (int i = 0; i < 4; ++i)
#pragma unroll
    for (int j = 0; j < 6; ++j) acc[i][j] = f32x4{0.f, 0.f, 0.f, 0.f};

  const ushort_t* Ag = A + (size_t)bm * 2048;
  const ushort_t* Bg = Bt + (size_t)bn * 2048;

#define STAGE(Ad, Bd, kk_)                                       \
  do {                                                           \
    for (int r2 = 0; r2 < 2; ++r2) {                             \
      int c_ = r2 * 256 + t;                                     \
      int row_ = c_ >> 2, s4_ = c_ & 3;                          \
      int slot_ = s4_ ^ ((row_ & 3) ^ ((row_ >> 2) & 3));        \
      g2lds16(Ag + row_ * 2048 + (kk_) + slot_ * 8, (Ad) + c_ * 8); \
    }                                                            \
    for (int r3 = 0; r3 < 3; ++r3) {                             \
      int c_ = r3 * 256 + t;                                     \
      int row_ = c_ >> 2, s4_ = c_ & 3;                          \
      int slot_ = s4_ ^ ((row_ & 3) ^ ((row_ >> 2) & 3));        \
      g2lds16(Bg + row_ * 2048 + (kk_) + slot_ * 8, (Bd) + c_ * 8); \
    }                                                            \
  } while (0)

  STAGE(A0, B0, 0);
  __syncthreads();
  ushort_t *Ac = A0, *Bc = B0, *An = A1, *Bn = B1;

  for (int kk = 0; kk < 2048; kk += 32) {
    if (kk + 32 < 2048) STAGE(An, Bn, kk + 32);  // issue next-tile loads EARLY
    bf16x8 af[4], bfr[6];
#pragma unroll
    for (int mf = 0; mf < 4; ++mf) {
      int row = wr * 64 + mf * 16 + lo;
      int fr = (row & 3) ^ ((row >> 2) & 3);
      af[mf] = ld_bf8(Ac + row * 32 + ((hi ^ fr) << 3));
    }
#pragma unroll
    for (int nf = 0; nf < 6; ++nf) {
      int row = wc * 96 + nf * 16 + lo;
      int fr = (row & 3) ^ ((row >> 2) & 3);
      bfr[nf] = ld_bf8(Bc + row * 32 + ((hi ^ fr) << 3));
    }
    __builtin_amdgcn_s_setprio(1);
#pragma unroll
    for (int mf = 0; mf < 4; ++mf)
#pragma unroll
      for (int nf = 0; nf < 6; ++nf)
        acc[mf][nf] = __builtin_amdgcn_mfma_f32_16x16x32_bf16(
            af[mf], bfr[nf], acc[mf][nf], 0, 0, 0);
    __builtin_amdgcn_s_setprio(0);
    __syncthreads();  // drains next-buffer vmcnt + fences current-buffer reads
    ushort_t* tmp;
    tmp = Ac; Ac = An; An = tmp;
    tmp = Bc; Bc = Bn; Bn = tmp;
  }
#undef STAGE

  // ---- epilogue: bias + de-interleave via LDS repack, coalesced stores ----
  float bv[6];
  int ch[6];
#pragma unroll
  for (int nf = 0; nf < 6; ++nf) {
    int nl = wc * 96 + nf * 16 + lo;
    bv[nf] = bias[bn + nl];
    ch[nf] = nl % 3;
  }
  const int b_ = bm >> 11;
  const int bh = (b_ << 5) + nt;  // head index == nt
  const float QS = 0.125f * 1.44269504f;

#pragma unroll
  for (int h = 0; h < 2; ++h) {
    if (wr == h) {
#pragma unroll
      for (int mf = 0; mf < 4; ++mf)
#pragma unroll
        for (int nf = 0; nf < 6; ++nf) {
          int rloc = mf * 16 + hi * 4;
          int nl = wc * 96 + nf * 16 + lo;
          f32x4 a = acc[mf][nf];
#pragma unroll
          for (int j = 0; j < 4; ++j) {
            float v = a[j] + bv[nf];
            if (ch[nf] == 0) v *= QS;
            Cs[(rloc + j) * 200 + nl] = f2bf(v);
          }
        }
    }
    __syncthreads();
    const int sbase = (bm & 2047) + h * 64;
#pragma unroll
    for (int it = 0; it < 2; ++it) {
      int slot = it * 256 + t;
      int r = slot >> 3, g = slot & 7;
      ushort8 vq, vk;
#pragma unroll
      for (int u = 0; u < 8; ++u) {
        int hd = g * 8 + u;
        vq[u] = Cs[r * 200 + hd * 3];
        vk[u] = Cs[r * 200 + hd * 3 + 2];
      }
      size_t rowoff = ((size_t)bh * 2048 + sbase + r) * 64 + g * 8;
      *reinterpret_cast<ushort8*>(Qb + rowoff) = vq;
      *reinterpret_cast<ushort8*>(Kb + rowoff) = vk;
    }
#pragma unroll
    for (int it = 0; it < 2; ++it) {
      int slot = it * 256 + t;
      int hd = slot >> 3, sg = slot & 7;
      ushort8 vv;
#pragma unroll
      for (int u = 0; u < 8; ++u) vv[u] = Cs[(sg * 8 + u) * 200 + hd * 3 + 1];
      *reinterpret_cast<ushort8*>(VT + ((size_t)bh * 64 + hd) * 2048 + sbase +
                                  sg * 8) = vv;
    }
    __syncthreads();
  }
}

// ---------------- Pass 2: causal flash attention, 1 wave / q-tile -----------
// R8-verified structure (simple loop, K+V prefetch, defer-max, shfl_xor
// exchanges — permlane is BANNED, 2 failures). Two algebraic shfl removals:
// (a) max-exchange only inside the (rare, wave-uniform) rescale branch —
//     __any() spans all 64 lanes so own-half mx gives the same trigger;
// (b) lr kept as own-half partial (scl is pair-identical), one exchange at end.
// Common path: 8 shfls/chunk (repack only), was 10.
__global__ __launch_bounds__(64) void attn(
    const ushort_t* __restrict__ Qb, const ushort_t* __restrict__ Kb,
    const ushort_t* __restrict__ VT, float* __restrict__ out) {
  __shared__ float Ld[32 * 66];  // 8448 B, wave-private
  const int l = threadIdx.x;
  const int ql = l & 31, hi = l >> 5;

  const int bid = blockIdx.x;
  const int bh = bid & 63;        // one bh per CU (L2 locality)
  const int qt = 63 - (bid >> 6); // uniform depth coverage per CU
  const int q0 = qt * 32;
  const int nch = qt + 1;

  const ushort_t* qp = Qb + (bh * 2048 + q0 + ql) * 64 + hi * 8;
  bf16x8 qf[4];
#pragma unroll
  for (int dc = 0; dc < 4; ++dc) qf[dc] = ld_bf8(qp + dc * 16);

  f32x16 o0, o1;
#pragma unroll
  for (int r = 0; r < 16; ++r) { o0[r] = 0.f; o1[r] = 0.f; }
  float mr = -1e30f, lr = 0.f;

  const ushort_t* kbase = Kb + bh * 2048 * 64 + hi * 8;
  const ushort_t* vbase = VT + (bh * 64 + ql) * 2048 + hi * 8;

  // preload chunk 0: K and V fragments
  bf16x8 kf[4], vf0[2], vf1[2];
  {
    const ushort_t* kp = kbase + ql * 64;
#pragma unroll
    for (int dc = 0; dc < 4; ++dc) kf[dc] = ld_bf8(kp + dc * 16);
#pragma unroll
    for (int s = 0; s < 2; ++s) {
      const ushort_t* vp = vbase + s * 16;
      vf0[s] = ld_bf8(vp);
      vf1[s] = ld_bf8(vp + 32 * 2048);
    }
  }

  for (int c = 0; c < nch; ++c) {
    const int cn = (c + 1 < nch) ? (c + 1) : c;
    // prefetch next chunk's K and V (clamped on last iter)
    const ushort_t* kpn = kbase + (cn * 32 + ql) * 64;
    bf16x8 kn[4], vn0[2], vn1[2];
#pragma unroll
    for (int dc = 0; dc < 4; ++dc) kn[dc] = ld_bf8(kpn + dc * 16);
#pragma unroll
    for (int s = 0; s < 2; ++s) {
      const ushort_t* vpn = vbase + cn * 32 + s * 16;
      vn0[s] = ld_bf8(vpn);
      vn1[s] = ld_bf8(vpn + 32 * 2048);
    }

    f32x16 p;
#pragma unroll
    for (int r = 0; r < 16; ++r) p[r] = 0.f;
    __builtin_amdgcn_s_setprio(1);
#pragma unroll
    for (int dc = 0; dc < 4; ++dc)
      p = __builtin_amdgcn_mfma_f32_32x32x16_bf16(kf[dc], qf[dc], p, 0, 0, 0);
    __builtin_amdgcn_s_setprio(0);
    if (c == nch - 1) {  // diagonal chunk: mask kv > q
#pragma unroll
      for (int r = 0; r < 16; ++r) {
        int kvr = (r & 3) + 8 * (r >> 2) + 4 * hi;
        if (kvr > ql) p[r] = -1e30f;
      }
    }
    // own-half pairwise-tree max (no cross-half exchange in common path)
    float a0 = fmaxf(p[0], p[1]), a1 = fmaxf(p[2], p[3]);
    float a2 = fmaxf(p[4], p[5]), a3 = fmaxf(p[6], p[7]);
    float a4 = fmaxf(p[8], p[9]), a5 = fmaxf(p[10], p[11]);
    float a6 = fmaxf(p[12], p[13]), a7 = fmaxf(p[14], p[15]);
    float mx = fmaxf(fmaxf(fmaxf(a0, a1), fmaxf(a2, a3)),
                     fmaxf(fmaxf(a4, a5), fmaxf(a6, a7)));
    // defer-max: __any spans all 64 lanes (both halves of every q column),
    // so own-half mx yields the identical wave-wide trigger. Exchange only
    // inside the (wave-uniform) rescale branch.
    if (__any(mx > mr + 10.0f)) {
      mx = fmaxf(mx, __shfl_xor(mx, 32));
      float mn = fmaxf(mr, mx);
      float scl = ex2(mr - mn);
      mr = mn;
      lr *= scl;
#pragma unroll
      for (int r = 0; r < 16; ++r) { o0[r] *= scl; o1[r] *= scl; }
    }
#pragma unroll
    for (int r = 0; r < 16; ++r) p[r] = ex2(p[r] - mr);
    float s0 = (p[0] + p[1]) + (p[2] + p[3]);
    float s1 = (p[4] + p[5]) + (p[6] + p[7]);
    float s2 = (p[8] + p[9]) + (p[10] + p[11]);
    float s3 = (p[12] + p[13]) + (p[14] + p[15]);
    lr += (s0 + s1) + (s2 + s3);  // own-half partial; merged in epilogue

    // P^T -> bf16 B-fragments, in-register (cvt_pk + lane^32 shfl exchange)
    __builtin_amdgcn_s_setprio(1);
#pragma unroll
    for (int s = 0; s < 2; ++s) {
      int x0 = cvtpk(p[8 * s + 0], p[8 * s + 1]);
      int x1 = cvtpk(p[8 * s + 2], p[8 * s + 3]);
      int y0 = cvtpk(p[8 * s + 4], p[8 * s + 5]);
      int y1 = cvtpk(p[8 * s + 6], p[8 * s + 7]);
      int ox0 = __shfl_xor(x0, 32);
      int ox1 = __shfl_xor(x1, 32);
      int oy0 = __shfl_xor(y0, 32);
      int oy1 = __shfl_xor(y1, 32);
      int4v wv;
      wv[0] = hi ? oy0 : x0;
      wv[1] = hi ? oy1 : x1;
      wv[2] = hi ? y0 : ox0;
      wv[3] = hi ? y1 : ox1;
      bf16x8 pf = __builtin_bit_cast(bf16x8, wv);
      o0 = __builtin_amdgcn_mfma_f32_32x32x16_bf16(vf0[s], pf, o0, 0, 0, 0);
      o1 = __builtin_amdgcn_mfma_f32_32x32x16_bf16(vf1[s], pf, o1, 0, 0, 0);
    }
    __builtin_amdgcn_s_setprio(0);
#pragma unroll
    for (int dc = 0; dc < 4; ++dc) kf[dc] = kn[dc];
#pragma unroll
    for (int s = 0; s < 2; ++s) {
      vf0[s] = vn0[s];
      vf1[s] = vn1[s];
    }
  }

  // epilogue: merge own-half lr partials (scl history pair-identical -> exact)
  const float lrf = lr + __shfl_xor(lr, 32);
  const float inv = 1.0f / lrf;
#pragma unroll
  for (int r = 0; r < 16; ++r) {
    int hdv = (r & 3) + 8 * (r >> 2) + 4 * hi;
    Ld[ql * 66 + hdv] = o0[r] * inv;
    Ld[ql * 66 + 32 + hdv] = o1[r] * inv;
  }
  __syncthreads();
  const int b_ = bh >> 5, h = bh & 31;
  float* op = out + (size_t)(b_ * 2048 + q0) * 2048 + h * 64 + l;
#pragma unroll
  for (int i = 0; i < 32; ++i) {
    op[(size_t)i * 2048] = Ld[i * 66 + l];
  }
}

// ---------------------------------------------------------------------------
extern "C" void kernel_launch(void* const* d_in, const int* in_sizes, int n_in,
                              void* d_out, int out_size, void* d_ws,
                              size_t ws_size, hipStream_t stream) {
  (void)in_sizes; (void)n_in; (void)out_size; (void)ws_size;
  const float* hs = (const float*)d_in[0];    // [2,2048,2048]
  const float* W = (const float*)d_in[1];     // [2048,6144]
  const float* bias = (const float*)d_in[2];  // [6144]
  float* out = (float*)d_out;

  char* ws = (char*)d_ws;
  ushort_t* Abf = (ushort_t*)(ws);                        // 16 MiB  [4096][2048]
  ushort_t* Wt = (ushort_t*)(ws + (16u << 20));           // 24 MiB  [6144][2048]
  ushort_t* Qb = (ushort_t*)(ws + (40u << 20));           // 16 MiB  [64][2048][64]
  ushort_t* Kb = (ushort_t*)(ws + (56u << 20));           // 16 MiB  [64][2048][64]
  ushort_t* VT = (ushort_t*)(ws + (72u << 20));           // 16 MiB  [64][64][2048]

  hipLaunchKernelGGL(cvt_hs, dim3(4096), dim3(256), 0, stream, hs, Abf);
  hipLaunchKernelGGL(transpose_W, dim3(3072), dim3(256), 0, stream, W, Wt);
  hipLaunchKernelGGL(gemm_qkv, dim3(1024), dim3(256), 0, stream, Abf, Wt, bias,
                     Qb, Kb, VT);
  hipLaunchKernelGGL(attn, dim3(4096), dim3(64), 0, stream, Qb, Kb, VT, out);
}

// Round 12
// 258.241 us; speedup vs baseline: 2.3488x; 1.0200x over previous
//
#include <hip/hip_runtime.h>
#include <hip/hip_bf16.h>
#include <stdint.h>

// Problem constants: B=2, S=2048, D=2048, H=32, HD=64, 3D=6144, M=B*S=4096, K=2048
typedef unsigned short ushort_t;
typedef __bf16 bf16x8 __attribute__((ext_vector_type(8)));
typedef float f32x4 __attribute__((ext_vector_type(4)));
typedef float f32x16 __attribute__((ext_vector_type(16)));
typedef int int4v __attribute__((ext_vector_type(4)));
typedef ushort_t ushort8 __attribute__((ext_vector_type(8)));

__device__ __forceinline__ ushort_t f2bf(float f) {
  union { float f; unsigned int u; } v; v.f = f;
  unsigned int r = v.u + 0x7fffu + ((v.u >> 16) & 1u);  // RNE
  return (ushort_t)(r >> 16);
}

__device__ __forceinline__ bf16x8 ld_bf8(const ushort_t* p) {
  return *reinterpret_cast<const bf16x8*>(p);
}

__device__ __forceinline__ void g2lds16(const void* g, void* l) {
  __builtin_amdgcn_global_load_lds(
      (const __attribute__((address_space(1))) unsigned int*)g,
      (__attribute__((address_space(3))) unsigned int*)l,
      16, 0, 0);
}

__device__ __forceinline__ float ex2(float x) { return __builtin_amdgcn_exp2f(x); }

// v_cvt_pk_bf16_f32: word = {lo: bf16(a), hi: bf16(b)}
__device__ __forceinline__ int cvtpk(float a, float b) {
  int r;
  asm("v_cvt_pk_bf16_f32 %0, %1, %2" : "=v"(r) : "v"(a), "v"(b));
  return r;
}

// ---------------- Pass 0a: hidden_states f32 -> bf16 (same layout) ----------
__global__ __launch_bounds__(256) void cvt_hs(const float* __restrict__ in,
                                              ushort_t* __restrict__ out) {
  int i = (blockIdx.x * 256 + threadIdx.x) * 8;
  float4 a = *reinterpret_cast<const float4*>(in + i);
  float4 b = *reinterpret_cast<const float4*>(in + i + 4);
  ushort8 r;
  r[0] = f2bf(a.x); r[1] = f2bf(a.y); r[2] = f2bf(a.z); r[3] = f2bf(a.w);
  r[4] = f2bf(b.x); r[5] = f2bf(b.y); r[6] = f2bf(b.z); r[7] = f2bf(b.w);
  *reinterpret_cast<ushort8*>(out + i) = r;
}

// ---------------- Pass 0b: W [2048][6144] f32 -> Wt [6144][2048] bf16 -------
__global__ __launch_bounds__(256) void transpose_W(const float* __restrict__ Win,
                                                   ushort_t* __restrict__ Wt) {
  __shared__ ushort_t T[64][65];
  const int t = threadIdx.x;
  const int k0 = (blockIdx.x & 31) * 64;
  const int n0 = (blockIdx.x >> 5) * 64;
#pragma unroll
  for (int i = 0; i < 16; ++i) {
    int idx = i * 256 + t;
    int r = idx >> 6, c = idx & 63;
    T[r][c] = f2bf(Win[(k0 + r) * 6144 + n0 + c]);
  }
  __syncthreads();
#pragma unroll
  for (int i = 0; i < 16; ++i) {
    int idx = i * 256 + t;
    int nr = idx >> 6, kc = idx & 63;
    Wt[(n0 + nr) * 2048 + k0 + kc] = T[kc][nr];
  }
}

// ---------------- Pass 1: QKV GEMM, head-aligned BN=192, T3-min pipeline ----
// (R9-verified: double-buffered LDS, STAGE(t+1) before compute, 1 barrier/iter)
__global__ __launch_bounds__(256, 2) void gemm_qkv(
    const ushort_t* __restrict__ A, const ushort_t* __restrict__ Bt,
    const float* __restrict__ bias,
    ushort_t* __restrict__ Qb, ushort_t* __restrict__ Kb,
    ushort_t* __restrict__ VT) {
  __shared__ __align__(16) char smem[40960];
  ushort_t* A0 = (ushort_t*)smem;             // [128][32] buf0
  ushort_t* A1 = (ushort_t*)(smem + 8192);    // buf1
  ushort_t* B0 = (ushort_t*)(smem + 16384);   // [192][32] buf0
  ushort_t* B1 = (ushort_t*)(smem + 28672);   // buf1
  ushort_t* Cs = (ushort_t*)smem;             // [64][200] epilogue alias
  const int t = threadIdx.x;
  const int w = t >> 6, l = t & 63;
  const int lo = l & 15, hi = l >> 4;
  const int wr = w >> 1, wc = w & 1;

  int bid = blockIdx.x;
  int swz = (bid & 7) * 128 + (bid >> 3);  // bijective (1024 = 8*128)
  const int mt = swz & 31, nt = swz >> 5;  // 32 x 32 tiles
  const int bm = mt * 128;
  const int bn = nt * 192;

  f32x4 acc[4][6];
#pragma unroll
  for (int i = 0; i < 4; ++i)
#pragma unroll
    for (int j = 0; j < 6; ++j) acc[i][j] = f32x4{0.f, 0.f, 0.f, 0.f};

  const ushort_t* Ag = A + (size_t)bm * 2048;
  const ushort_t* Bg = Bt + (size_t)bn * 2048;

#define STAGE(Ad, Bd, kk_)                                       \
  do {                                                           \
    for (int r2 = 0; r2 < 2; ++r2) {                             \
      int c_ = r2 * 256 + t;                                     \
      int row_ = c_ >> 2, s4_ = c_ & 3;                          \
      int slot_ = s4_ ^ ((row_ & 3) ^ ((row_ >> 2) & 3));        \
      g2lds16(Ag + row_ * 2048 + (kk_) + slot_ * 8, (Ad) + c_ * 8); \
    }                                                            \
    for (int r3 = 0; r3 < 3; ++r3) {                             \
      int c_ = r3 * 256 + t;                                     \
      int row_ = c_ >> 2, s4_ = c_ & 3;                          \
      int slot_ = s4_ ^ ((row_ & 3) ^ ((row_ >> 2) & 3));        \
      g2lds16(Bg + row_ * 2048 + (kk_) + slot_ * 8, (Bd) + c_ * 8); \
    }                                                            \
  } while (0)

  STAGE(A0, B0, 0);
  __syncthreads();
  ushort_t *Ac = A0, *Bc = B0, *An = A1, *Bn = B1;

  for (int kk = 0; kk < 2048; kk += 32) {
    if (kk + 32 < 2048) STAGE(An, Bn, kk + 32);  // issue next-tile loads EARLY
    bf16x8 af[4], bfr[6];
#pragma unroll
    for (int mf = 0; mf < 4; ++mf) {
      int row = wr * 64 + mf * 16 + lo;
      int fr = (row & 3) ^ ((row >> 2) & 3);
      af[mf] = ld_bf8(Ac + row * 32 + ((hi ^ fr) << 3));
    }
#pragma unroll
    for (int nf = 0; nf < 6; ++nf) {
      int row = wc * 96 + nf * 16 + lo;
      int fr = (row & 3) ^ ((row >> 2) & 3);
      bfr[nf] = ld_bf8(Bc + row * 32 + ((hi ^ fr) << 3));
    }
    __builtin_amdgcn_s_setprio(1);
#pragma unroll
    for (int mf = 0; mf < 4; ++mf)
#pragma unroll
      for (int nf = 0; nf < 6; ++nf)
        acc[mf][nf] = __builtin_amdgcn_mfma_f32_16x16x32_bf16(
            af[mf], bfr[nf], acc[mf][nf], 0, 0, 0);
    __builtin_amdgcn_s_setprio(0);
    __syncthreads();  // drains next-buffer vmcnt + fences current-buffer reads
    ushort_t* tmp;
    tmp = Ac; Ac = An; An = tmp;
    tmp = Bc; Bc = Bn; Bn = tmp;
  }
#undef STAGE

  // ---- epilogue: bias + de-interleave via LDS repack, coalesced stores ----
  float bv[6];
  int ch[6];
#pragma unroll
  for (int nf = 0; nf < 6; ++nf) {
    int nl = wc * 96 + nf * 16 + lo;
    bv[nf] = bias[bn + nl];
    ch[nf] = nl % 3;
  }
  const int b_ = bm >> 11;
  const int bh = (b_ << 5) + nt;  // head index == nt
  const float QS = 0.125f * 1.44269504f;

#pragma unroll
  for (int h = 0; h < 2; ++h) {
    if (wr == h) {
#pragma unroll
      for (int mf = 0; mf < 4; ++mf)
#pragma unroll
        for (int nf = 0; nf < 6; ++nf) {
          int rloc = mf * 16 + hi * 4;
          int nl = wc * 96 + nf * 16 + lo;
          f32x4 a = acc[mf][nf];
#pragma unroll
          for (int j = 0; j < 4; ++j) {
            float v = a[j] + bv[nf];
            if (ch[nf] == 0) v *= QS;
            Cs[(rloc + j) * 200 + nl] = f2bf(v);
          }
        }
    }
    __syncthreads();
    const int sbase = (bm & 2047) + h * 64;
#pragma unroll
    for (int it = 0; it < 2; ++it) {
      int slot = it * 256 + t;
      int r = slot >> 3, g = slot & 7;
      ushort8 vq, vk;
#pragma unroll
      for (int u = 0; u < 8; ++u) {
        int hd = g * 8 + u;
        vq[u] = Cs[r * 200 + hd * 3];
        vk[u] = Cs[r * 200 + hd * 3 + 2];
      }
      size_t rowoff = ((size_t)bh * 2048 + sbase + r) * 64 + g * 8;
      *reinterpret_cast<ushort8*>(Qb + rowoff) = vq;
      *reinterpret_cast<ushort8*>(Kb + rowoff) = vk;
    }
#pragma unroll
    for (int it = 0; it < 2; ++it) {
      int slot = it * 256 + t;
      int hd = slot >> 3, sg = slot & 7;
      ushort8 vv;
#pragma unroll
      for (int u = 0; u < 8; ++u) vv[u] = Cs[(sg * 8 + u) * 200 + hd * 3 + 1];
      *reinterpret_cast<ushort8*>(VT + ((size_t)bh * 64 + hd) * 2048 + sbase +
                                  sg * 8) = vv;
    }
    __syncthreads();
  }
}

// ---------------- attn helpers (R11-verified math, byte-identical) ----------
__device__ __forceinline__ void ldkv(const ushort_t* kp, const ushort_t* vp,
                                     bf16x8 k[4], bf16x8 v0[2], bf16x8 v1[2]) {
#pragma unroll
  for (int dc = 0; dc < 4; ++dc) k[dc] = ld_bf8(kp + dc * 16);
#pragma unroll
  for (int s = 0; s < 2; ++s) {
    v0[s] = ld_bf8(vp + s * 16);
    v1[s] = ld_bf8(vp + s * 16 + 32 * 2048);
  }
}

__device__ __forceinline__ void proc_chunk(const bf16x8 kf[4],
                                           const bf16x8 vf0[2],
                                           const bf16x8 vf1[2],
                                           const bf16x8 qf[4], f32x16& o0,
                                           f32x16& o1, float& mr, float& lr,
                                           bool diag, int ql, int hi) {
  f32x16 p;
#pragma unroll
  for (int r = 0; r < 16; ++r) p[r] = 0.f;
  __builtin_amdgcn_s_setprio(1);
#pragma unroll
  for (int dc = 0; dc < 4; ++dc)
    p = __builtin_amdgcn_mfma_f32_32x32x16_bf16(kf[dc], qf[dc], p, 0, 0, 0);
  __builtin_amdgcn_s_setprio(0);
  if (diag) {  // diagonal chunk: mask kv > q
#pragma unroll
    for (int r = 0; r < 16; ++r) {
      int kvr = (r & 3) + 8 * (r >> 2) + 4 * hi;
      if (kvr > ql) p[r] = -1e30f;
    }
  }
  // own-half pairwise-tree max (no cross-half exchange in common path)
  float a0 = fmaxf(p[0], p[1]), a1 = fmaxf(p[2], p[3]);
  float a2 = fmaxf(p[4], p[5]), a3 = fmaxf(p[6], p[7]);
  float a4 = fmaxf(p[8], p[9]), a5 = fmaxf(p[10], p[11]);
  float a6 = fmaxf(p[12], p[13]), a7 = fmaxf(p[14], p[15]);
  float mx = fmaxf(fmaxf(fmaxf(a0, a1), fmaxf(a2, a3)),
                   fmaxf(fmaxf(a4, a5), fmaxf(a6, a7)));
  // defer-max: __any spans all 64 lanes -> own-half mx gives identical
  // wave-wide trigger; exchange only inside the (wave-uniform) branch.
  if (__any(mx > mr + 10.0f)) {
    mx = fmaxf(mx, __shfl_xor(mx, 32));
    float mn = fmaxf(mr, mx);
    float scl = ex2(mr - mn);
    mr = mn;
    lr *= scl;
#pragma unroll
    for (int r = 0; r < 16; ++r) { o0[r] *= scl; o1[r] *= scl; }
  }
#pragma unroll
  for (int r = 0; r < 16; ++r) p[r] = ex2(p[r] - mr);
  float s0 = (p[0] + p[1]) + (p[2] + p[3]);
  float s1 = (p[4] + p[5]) + (p[6] + p[7]);
  float s2 = (p[8] + p[9]) + (p[10] + p[11]);
  float s3 = (p[12] + p[13]) + (p[14] + p[15]);
  lr += (s0 + s1) + (s2 + s3);  // own-half partial; merged in epilogue

  // P^T -> bf16 B-fragments, in-register (cvt_pk + lane^32 shfl exchange)
  __builtin_amdgcn_s_setprio(1);
#pragma unroll
  for (int s = 0; s < 2; ++s) {
    int x0 = cvtpk(p[8 * s + 0], p[8 * s + 1]);
    int x1 = cvtpk(p[8 * s + 2], p[8 * s + 3]);
    int y0 = cvtpk(p[8 * s + 4], p[8 * s + 5]);
    int y1 = cvtpk(p[8 * s + 6], p[8 * s + 7]);
    int ox0 = __shfl_xor(x0, 32);
    int ox1 = __shfl_xor(x1, 32);
    int oy0 = __shfl_xor(y0, 32);
    int oy1 = __shfl_xor(y1, 32);
    int4v wv;
    wv[0] = hi ? oy0 : x0;
    wv[1] = hi ? oy1 : x1;
    wv[2] = hi ? y0 : ox0;
    wv[3] = hi ? y1 : ox1;
    bf16x8 pf = __builtin_bit_cast(bf16x8, wv);
    o0 = __builtin_amdgcn_mfma_f32_32x32x16_bf16(vf0[s], pf, o0, 0, 0, 0);
    o1 = __builtin_amdgcn_mfma_f32_32x32x16_bf16(vf1[s], pf, o1, 0, 0, 0);
  }
  __builtin_amdgcn_s_setprio(0);
}

// ---------------- Pass 2: causal flash attention, 1 wave, paired q-tiles ----
// grid = 2048 one-wave blocks. Each wave processes tiles qt=p and qt=63-p
// sequentially -> exactly 65 chunks per wave (zero variance, no tail).
// bh = bid&63: all blocks on a CU share one bh (L2 locality preserved).
// Loop: ping-pong A/B register sets (no copies), unconditional ptr-increment
// prefetch 1 chunk ahead, last chunk peeled. Math identical to R11.
__global__ __launch_bounds__(64) void attn(
    const ushort_t* __restrict__ Qb, const ushort_t* __restrict__ Kb,
    const ushort_t* __restrict__ VT, float* __restrict__ out) {
  __shared__ float Ld[32 * 66];  // 8448 B, wave-private
  const int l = threadIdx.x;
  const int ql = l & 31, hi = l >> 5;

  const int bid = blockIdx.x;
  const int bh = bid & 63;
  const int pr = bid >> 6;  // pair index 0..31
  const int b_ = bh >> 5, h = bh & 31;

  const ushort_t* kbase = Kb + bh * 2048 * 64 + hi * 8;
  const ushort_t* vbase = VT + (bh * 64 + ql) * 2048 + hi * 8;
  const int KSTR = 32 * 64;  // K row-stride per chunk (elements)
  const int VSTR = 32;       // V col-stride per chunk

#pragma unroll 1
  for (int tile = 0; tile < 2; ++tile) {
    const int qt = tile ? (63 - pr) : pr;
    const int q0 = qt * 32;
    const int nch = qt + 1;

    const ushort_t* qp = Qb + (bh * 2048 + q0 + ql) * 64 + hi * 8;
    bf16x8 qf[4];
#pragma unroll
    for (int dc = 0; dc < 4; ++dc) qf[dc] = ld_bf8(qp + dc * 16);

    f32x16 o0, o1;
#pragma unroll
    for (int r = 0; r < 16; ++r) { o0[r] = 0.f; o1[r] = 0.f; }
    float mr = -1e30f, lr = 0.f;

    bf16x8 kA[4], vA0[2], vA1[2], kB[4], vB0[2], vB1[2];
    const ushort_t* kp = kbase + ql * 64;
    const ushort_t* vp = vbase;
    ldkv(kp, vp, kA, vA0, vA1);  // chunk 0 -> A

    int c = 0;
    while (c + 2 <= nch) {
      kp += KSTR; vp += VSTR;
      ldkv(kp, vp, kB, vB0, vB1);  // chunk c+1 -> B (issued before proc A)
      proc_chunk(kA, vA0, vA1, qf, o0, o1, mr, lr, false, ql, hi);  // chunk c
      if (c + 2 < nch) {
        kp += KSTR; vp += VSTR;
        ldkv(kp, vp, kA, vA0, vA1);  // chunk c+2 -> A
      }
      proc_chunk(kB, vB0, vB1, qf, o0, o1, mr, lr, (c + 1 == nch - 1), ql, hi);
      c += 2;
    }
    if (c < nch) {  // odd remainder: final (diagonal) chunk in A
      proc_chunk(kA, vA0, vA1, qf, o0, o1, mr, lr, true, ql, hi);
    }

    // epilogue: merge own-half lr partials (scl history pair-identical)
    const float lrf = lr + __shfl_xor(lr, 32);
    const float inv = 1.0f / lrf;
#pragma unroll
    for (int r = 0; r < 16; ++r) {
      int hdv = (r & 3) + 8 * (r >> 2) + 4 * hi;
      Ld[ql * 66 + hdv] = o0[r] * inv;
      Ld[ql * 66 + 32 + hdv] = o1[r] * inv;
    }
    __syncthreads();
    float* op = out + (size_t)(b_ * 2048 + q0) * 2048 + h * 64 + l;
#pragma unroll
    for (int i = 0; i < 32; ++i) {
      op[(size_t)i * 2048] = Ld[i * 66 + l];
    }
    __syncthreads();
  }
}

// ---------------------------------------------------------------------------
extern "C" void kernel_launch(void* const* d_in, const int* in_sizes, int n_in,
                              void* d_out, int out_size, void* d_ws,
                              size_t ws_size, hipStream_t stream) {
  (void)in_sizes; (void)n_in; (void)out_size; (void)ws_size;
  const float* hs = (const float*)d_in[0];    // [2,2048,2048]
  const float* W = (const float*)d_in[1];     // [2048,6144]
  const float* bias = (const float*)d_in[2];  // [6144]
  float* out = (float*)d_out;

  char* ws = (char*)d_ws;
  ushort_t* Abf = (ushort_t*)(ws);                        // 16 MiB  [4096][2048]
  ushort_t* Wt = (ushort_t*)(ws + (16u << 20));           // 24 MiB  [6144][2048]
  ushort_t* Qb = (ushort_t*)(ws + (40u << 20));           // 16 MiB  [64][2048][64]
  ushort_t* Kb = (ushort_t*)(ws + (56u << 20));           // 16 MiB  [64][2048][64]
  ushort_t* VT = (ushort_t*)(ws + (72u << 20));           // 16 MiB  [64][64][2048]

  hipLaunchKernelGGL(cvt_hs, dim3(4096), dim3(256), 0, stream, hs, Abf);
  hipLaunchKernelGGL(transpose_W, dim3(3072), dim3(256), 0, stream, W, Wt);
  hipLaunchKernelGGL(gemm_qkv, dim3(1024), dim3(256), 0, stream, Abf, Wt, bias,
                     Qb, Kb, VT);
  hipLaunchKernelGGL(attn, dim3(2048), dim3(64), 0, stream, Qb, Kb, VT, out);
}